// Round 12
// baseline (406.965 us; speedup 1.0000x reference)
//
#include <hip/hip_runtime.h>

#define S_LEN  4096
#define DMODEL 1024
#define NHEAD  16
#define HDIM   64

typedef float    f32x4  __attribute__((ext_vector_type(4)));
typedef float    f32x16 __attribute__((ext_vector_type(16)));
typedef _Float16 f16x8  __attribute__((ext_vector_type(8)));
typedef _Float16 f16x4v __attribute__((ext_vector_type(4)));
typedef __fp16   fp16x2 __attribute__((ext_vector_type(2)));
typedef unsigned int u32;
typedef u32 u32x4 __attribute__((ext_vector_type(4)));

// ---------------------------------------------------------------- helpers
__device__ __forceinline__ void gl2lds16(const _Float16* g, _Float16* l) {
  __builtin_amdgcn_global_load_lds(
      (const __attribute__((address_space(1))) unsigned int*)g,
      (__attribute__((address_space(3))) unsigned int*)l, 16, 0, 0);
}

__device__ __forceinline__ u32 pkrtz_u(float a, float b) {
  fp16x2 h = __builtin_amdgcn_cvt_pkrtz(a, b);
  return __builtin_bit_cast(u32, h);
}

__device__ __forceinline__ float m3(float a, float b, float c) {
  return fmaxf(fmaxf(a, b), c);   // clang fuses to v_max3_f32
}

// attention schedule: 256-q-row blocks, parts(jb) tuned to ~8-12 tiles/part.
// parts: jb0-2:1, jb3-5:2, jb6-7:3, jb8-10:4, jb11-13:5, jb14-15:6 (sum 54/head)
__device__ __constant__ unsigned char PARTS_OF[16] =
  {1,1,1,2,2,2,3,3,4,4,4,5,5,5,6,6};
__device__ __constant__ unsigned char OFF_OF[16] =      // partial-unit prefix (jb>=3)
  {0,0,0,0,2,4,6,9,12,16,20,24,29,34,39,45};            // total 51/head
__device__ __constant__ unsigned char JB_TAB[54] = {    // LPT: heaviest parts first
  2, 5,5, 13,13,13,13,13, 10,10,10,10, 7,7,7,
  15,15,15,15,15,15, 12,12,12,12,12, 4,4, 9,9,9,9,
  14,14,14,14,14,14, 11,11,11,11,11, 6,6,6, 8,8,8,8,
  3,3, 1, 0};
__device__ __constant__ unsigned char PT_TAB[54] = {
  0, 0,1, 0,1,2,3,4, 0,1,2,3, 0,1,2,
  0,1,2,3,4,5, 0,1,2,3,4, 0,1, 0,1,2,3,
  0,1,2,3,4,5, 0,1,2,3,4, 0,1,2, 0,1,2,3,
  0,1, 0, 0};

// ---------------------------------------------------------------- casts
__global__ void cast_f32_f16_k(const float* __restrict__ in,
                               _Float16* __restrict__ out, int n) {
  int i = (blockIdx.x * blockDim.x + threadIdx.x) * 4;
  if (i + 3 < n) {
    const float4 v = *(const float4*)(in + i);
    f16x4v o = { (_Float16)v.x, (_Float16)v.y, (_Float16)v.z, (_Float16)v.w };
    *(f16x4v*)(out + i) = o;
  }
}

__global__ void cast4_k(const float* __restrict__ a, const float* __restrict__ b,
                        const float* __restrict__ c, const float* __restrict__ d,
                        _Float16* __restrict__ oa, _Float16* __restrict__ ob,
                        _Float16* __restrict__ oc, _Float16* __restrict__ od) {
  const int seg = blockIdx.y;
  const float* in = seg == 0 ? a : seg == 1 ? b : seg == 2 ? c : d;
  _Float16*   out = seg == 0 ? oa : seg == 1 ? ob : seg == 2 ? oc : od;
  const int i = (blockIdx.x * blockDim.x + threadIdx.x) * 4;
  const float4 v = *(const float4*)(in + i);
  f16x4v o = { (_Float16)v.x, (_Float16)v.y, (_Float16)v.z, (_Float16)v.w };
  *(f16x4v*)(out + i) = o;
}

// ---------------------------------------------------------------- fused QKV GEMM
__global__ __launch_bounds__(256)
void gemm_qkv(const _Float16* __restrict__ A,
              const _Float16* __restrict__ Bw,
              const float* __restrict__ bq,
              const float* __restrict__ bk,
              const float* __restrict__ bv,
              const float* __restrict__ ts,
              _Float16* __restrict__ Qb,
              _Float16* __restrict__ Kb,
              _Float16* __restrict__ Vtb)
{
  __shared__ _Float16 lA[128 * 64];
  __shared__ _Float16 lB[128 * 64];

  const int tid  = threadIdx.x;
  const int wid  = tid >> 6;
  const int lane = tid & 63;
  const int l16  = lane & 15;
  const int lg   = lane >> 4;
  const int wr = wid >> 1, wc = wid & 1;
  const int m0 = blockIdx.y * 128, n0 = blockIdx.x * 128;
  const int K = DMODEL, M = S_LEN;

  const int lrow   = lane >> 3;
  const int gchunk = (lane & 7) ^ lrow;

  f32x4 acc[4][4] = {};

  for (int k0 = 0; k0 < K; k0 += 64) {
#pragma unroll
    for (int it = 0; it < 4; ++it) {
      const int rbase = (it * 4 + wid) * 8;
      gl2lds16(A  + (size_t)(m0 + rbase + lrow) * K + k0 + gchunk * 8, &lA[rbase * 64]);
      gl2lds16(Bw + (size_t)(n0 + rbase + lrow) * K + k0 + gchunk * 8, &lB[rbase * 64]);
    }
    __syncthreads();
#pragma unroll
    for (int kk = 0; kk < 2; ++kk) {
      f16x8 af[4], bfr[4];
#pragma unroll
      for (int mr = 0; mr < 4; ++mr) {
        const int row = wr * 64 + mr * 16 + l16;
        const int ch  = (kk * 4 + lg) ^ (l16 & 7);
        af[mr] = *(const f16x8*)&lA[row * 64 + ch * 8];
      }
#pragma unroll
      for (int nr = 0; nr < 4; ++nr) {
        const int row = wc * 64 + nr * 16 + l16;
        const int ch  = (kk * 4 + lg) ^ (l16 & 7);
        bfr[nr] = *(const f16x8*)&lB[row * 64 + ch * 8];
      }
#pragma unroll
      for (int mr = 0; mr < 4; ++mr)
#pragma unroll
        for (int nr = 0; nr < 4; ++nr)
          acc[mr][nr] = __builtin_amdgcn_mfma_f32_16x16x32_f16(af[mr], bfr[nr], acc[mr][nr], 0, 0, 0);
    }
    __syncthreads();
  }

  if (n0 >= 2048) {           // ---- V: bias + transposed store
    const int dbase = n0 - 2048;
    float bvv[4];
#pragma unroll
    for (int nr = 0; nr < 4; ++nr) bvv[nr] = bv[dbase + wc * 64 + nr * 16 + l16];
#pragma unroll
    for (int mr = 0; mr < 4; ++mr) {
      const int mbase = m0 + wr * 64 + mr * 16 + lg * 4;
#pragma unroll
      for (int nr = 0; nr < 4; ++nr) {
        const int d = dbase + wc * 64 + nr * 16 + l16;
        f16x4v o = { (_Float16)(acc[mr][nr][0] + bvv[nr]),
                     (_Float16)(acc[mr][nr][1] + bvv[nr]),
                     (_Float16)(acc[mr][nr][2] + bvv[nr]),
                     (_Float16)(acc[mr][nr][3] + bvv[nr]) };
        *(f16x4v*)&Vtb[(size_t)d * M + mbase] = o;
      }
    }
  } else {                    // ---- Q or K: bias + CT-RoPE
    _Float16* O = (n0 < 1024) ? Qb : Kb;
    const float* bias = (n0 < 1024) ? bq : bk;
    const int nloc = n0 & 1023;
    float bvv[4];
#pragma unroll
    for (int nr = 0; nr < 4; ++nr) bvv[nr] = bias[nloc + wc * 64 + nr * 16 + l16];
    const float L2T  = 13.287712379549449f / 32.0f;   // log2(10000)/32
    const float inv0 = exp2f(-(float)l16 * L2T);
    const float inv1 = exp2f(-(float)(l16 + 16) * L2T);
#pragma unroll
    for (int mr = 0; mr < 4; ++mr)
#pragma unroll
      for (int r = 0; r < 4; ++r) {
        const int m = m0 + wr * 64 + mr * 16 + lg * 4 + r;
        const float t = ts[m];
        float s0, c0, s1, c1;
        sincosf(t * inv0, &s0, &c0);
        sincosf(t * inv1, &s1, &c1);
        const float p0 = acc[mr][0][r] + bvv[0];
        const float p1 = acc[mr][1][r] + bvv[1];
        const float p2 = acc[mr][2][r] + bvv[2];
        const float p3 = acc[mr][3][r] + bvv[3];
        const size_t base = (size_t)m * DMODEL + nloc + wc * 64 + l16;
        O[base + 0 ] = (_Float16)(p0 * c0 - p2 * s0);
        O[base + 16] = (_Float16)(p1 * c1 - p3 * s1);
        O[base + 32] = (_Float16)(p2 * c0 + p0 * s0);
        O[base + 48] = (_Float16)(p3 * c1 + p1 * s1);
      }
  }
}

// ---------------------------------------------------------------- O-proj GEMM (f32 out)
// 64x128 tile -> grid (8,64) = 512 blocks = 2/CU.
__global__ __launch_bounds__(256)
void gemm_o(const _Float16* __restrict__ A,
            const _Float16* __restrict__ Bw,
            float* __restrict__ O)
{
  __shared__ _Float16 lA[64 * 64];
  __shared__ _Float16 lB[128 * 64];

  const int tid  = threadIdx.x;
  const int wid  = tid >> 6;
  const int lane = tid & 63;
  const int l16  = lane & 15;
  const int lg   = lane >> 4;
  const int wr = wid >> 1, wc = wid & 1;
  const int m0 = blockIdx.y * 64, n0 = blockIdx.x * 128;
  const int K = DMODEL, N = DMODEL;

  const int lrow   = lane >> 3;
  const int gchunk = (lane & 7) ^ lrow;

  f32x4 acc[2][4] = {};

  for (int k0 = 0; k0 < K; k0 += 64) {
#pragma unroll
    for (int it = 0; it < 2; ++it) {
      const int rbase = (it * 4 + wid) * 8;
      gl2lds16(A + (size_t)(m0 + rbase + lrow) * K + k0 + gchunk * 8, &lA[rbase * 64]);
    }
#pragma unroll
    for (int it = 0; it < 4; ++it) {
      const int rbase = (it * 4 + wid) * 8;
      gl2lds16(Bw + (size_t)(n0 + rbase + lrow) * K + k0 + gchunk * 8, &lB[rbase * 64]);
    }
    __syncthreads();
#pragma unroll
    for (int kk = 0; kk < 2; ++kk) {
      f16x8 af[2], bfr[4];
#pragma unroll
      for (int mr = 0; mr < 2; ++mr) {
        const int row = wr * 32 + mr * 16 + l16;
        const int ch  = (kk * 4 + lg) ^ (l16 & 7);
        af[mr] = *(const f16x8*)&lA[row * 64 + ch * 8];
      }
#pragma unroll
      for (int nr = 0; nr < 4; ++nr) {
        const int row = wc * 64 + nr * 16 + l16;
        const int ch  = (kk * 4 + lg) ^ (l16 & 7);
        bfr[nr] = *(const f16x8*)&lB[row * 64 + ch * 8];
      }
#pragma unroll
      for (int mr = 0; mr < 2; ++mr)
#pragma unroll
        for (int nr = 0; nr < 4; ++nr)
          acc[mr][nr] = __builtin_amdgcn_mfma_f32_16x16x32_f16(af[mr], bfr[nr], acc[mr][nr], 0, 0, 0);
    }
    __syncthreads();
  }

#pragma unroll
  for (int mr = 0; mr < 2; ++mr)
#pragma unroll
    for (int r = 0; r < 4; ++r) {
      const int m = m0 + wr * 32 + mr * 16 + lg * 4 + r;
#pragma unroll
      for (int nr = 0; nr < 4; ++nr) {
        const int n = n0 + wc * 64 + nr * 16 + l16;
        O[(size_t)m * N + n] = acc[mr][nr][r];
      }
    }
}

// ---------------------------------------------------------------- flash attention v10
// 864 blocks x 512 thr (8 waves x 32 q = 256 q-rows/block). 4 blocks/CU
// (36.9KB LDS) -> 32-wave/CU ceiling. K/V staging shared by 8 waves.
// kv-split per PARTS_OF (~8-12 tiles/part), static LPT tables.
__device__ __forceinline__ void stage_tiles(const _Float16* __restrict__ Km,
                                            const _Float16* __restrict__ Vt,
                                            _Float16* kdst, _Float16* vdst,
                                            int kv0, int h, int wid, int lane) {
  const int rb  = wid * 8;                 // 8 waves cover 64 rows
  const int row = rb + (lane >> 3);
  const int g   = (lane & 7) ^ (row & 7);  // pre-swizzled source chunk
  gl2lds16(Km + (size_t)(kv0 + row) * DMODEL + h * HDIM + g * 8, kdst + rb * 64);
  gl2lds16(Vt + (size_t)(h * HDIM + row) * S_LEN + kv0 + g * 8, vdst + rb * 64);
}

__global__ __launch_bounds__(512, 8)
void attn_fwd(const _Float16* __restrict__ Q,
              const _Float16* __restrict__ Km,
              const _Float16* __restrict__ Vt,
              _Float16* __restrict__ Om,
              _Float16* __restrict__ pO0,
              _Float16* __restrict__ pO1,
              float* __restrict__ ps)
{
  // staging: [buf][K|V] 4x4096 f16 = 32KB at offsets 0/4096/8192/12288.
  // epilogue transpose: 8 waves x 2304 f16 = 18432 f16 = 36.9KB total.
  __shared__ __align__(16) _Float16 smem[18432];

  const int tid  = threadIdx.x;
  const int wid  = tid >> 6, lane = tid & 63;
  const int l31  = lane & 31;
  const bool hi  = (lane & 32) != 0;
  const int flat = blockIdx.x, xcd = flat & 7, idx = flat >> 3;  // idx 0..107
  const int h    = xcd * 2 + (idx & 1);
  const int slot = idx >> 1;                  // 0..53, LPT order
  const int jb    = JB_TAB[slot];
  const int part  = PT_TAB[slot];
  const int parts = PARTS_OF[jb];
  const int nt  = 4 * (jb + 1);
  const int kt0 = (nt * part) / parts, kt1 = (nt * (part + 1)) / parts;
  const bool partial = parts > 1;
  const int u = partial ? (h * 51 + OFF_OF[jb] + part) : 0;
  const int q0w = jb * 256 + wid * 32;
  const int sw  = l31 & 7;                    // LDS read swizzle

  // Q B-fragments, pre-scaled by (1/sqrt(64))*log2(e)
  f16x8 qf[4];
  {
    const float qs = 0.18033688f;
    const size_t qbase = (size_t)(q0w + l31) * DMODEL + h * HDIM + (hi ? 8 : 0);
#pragma unroll
    for (int ks = 0; ks < 4; ++ks) {
      f16x8 t = *(const f16x8*)&Q[qbase + ks * 16];
#pragma unroll
      for (int e = 0; e < 8; ++e) qf[ks][e] = (_Float16)((float)t[e] * qs);
    }
  }

  f32x16 acc0, acc1;
#pragma unroll
  for (int r = 0; r < 16; ++r) { acc0[r] = 0.f; acc1[r] = 0.f; }
  float m_run = 0.f, l_run = 0.f;   // scores tracked as S - m_run; m starts 0

  stage_tiles(Km, Vt, &smem[0], &smem[4096], kt0 * 64, h, wid, lane);
  __syncthreads();
  int cur = 0;

  for (int kt = kt0; kt < kt1; ++kt) {
    if (kt + 1 < kt1)
      stage_tiles(Km, Vt, &smem[(cur ^ 1) * 8192], &smem[(cur ^ 1) * 8192 + 4096],
                  (kt + 1) * 64, h, wid, lane);

    const int kv0 = kt * 64;
    if (kv0 <= q0w + 31) {           // wave has at least one unmasked column
      const _Float16* kb = &smem[cur * 8192];
      const _Float16* vb = &smem[cur * 8192 + 4096];

      // ---- S^T - m_run = K . Q^T + (-m_run)  (rows = kv, cols = q)
      f32x16 s0, s1;
#pragma unroll
      for (int r = 0; r < 16; ++r) { s0[r] = -m_run; s1[r] = -m_run; }
      __builtin_amdgcn_s_setprio(1);
#pragma unroll
      for (int ks = 0; ks < 4; ++ks) {
        const int cs = ((ks * 2 + (hi ? 1 : 0)) ^ sw) * 8;
        const f16x8 ka0 = *(const f16x8*)&kb[l31 * 64 + cs];
        const f16x8 ka1 = *(const f16x8*)&kb[(32 + l31) * 64 + cs];
        s0 = __builtin_amdgcn_mfma_f32_32x32x16_f16(ka0, qf[ks], s0, 0, 0, 0);
        s1 = __builtin_amdgcn_mfma_f32_32x32x16_f16(ka1, qf[ks], s1, 0, 0, 0);
      }
      __builtin_amdgcn_s_setprio(0);

      if (kv0 + 63 > q0w) {          // diagonal tile: causal mask
        const int q = q0w + l31;
#pragma unroll
        for (int r = 0; r < 16; ++r) {
          const int kvr = kv0 + (r & 3) + 8 * (r >> 2) + (hi ? 4 : 0);
          if (kvr > q)      s0[r] = -1e30f;
          if (kvr + 32 > q) s1[r] = -1e30f;
        }
      }

      // ---- online softmax (exp2 domain), lane-local rows, defer-max
      float t10[10];
#pragma unroll
      for (int p = 0; p < 5; ++p) {
        t10[p]     = m3(s0[3*p], s0[3*p+1], s0[3*p+2]);
        t10[5 + p] = m3(s1[3*p], s1[3*p+1], s1[3*p+2]);
      }
      float u0 = m3(t10[0], t10[1], t10[2]);
      float u1 = m3(t10[3], t10[4], s0[15]);
      float u2 = m3(t10[5], t10[6], t10[7]);
      float u3 = m3(t10[8], t10[9], s1[15]);
      float pm = fmaxf(m3(u0, u1, u2), u3);
      pm = fmaxf(pm, __shfl_xor(pm, 32));

      if (!__all(pm <= 10.f)) {      // rescale (rare after first tile)
        m_run += pm;
        const float scl = exp2f(-pm);
        l_run *= scl;
#pragma unroll
        for (int r = 0; r < 16; ++r) { acc0[r] *= scl; acc1[r] *= scl; }
#pragma unroll
        for (int r = 0; r < 16; ++r) { s0[r] -= pm; s1[r] -= pm; }
      }

      float sa = 0.f, sb = 0.f, sc = 0.f, sd = 0.f;
#pragma unroll
      for (int r = 0; r < 16; r += 2) {
        s0[r]   = exp2f(s0[r]);
        s0[r+1] = exp2f(s0[r+1]);
        s1[r]   = exp2f(s1[r]);
        s1[r+1] = exp2f(s1[r+1]);
        sa += s0[r]; sb += s0[r+1]; sc += s1[r]; sd += s1[r+1];
      }
      float rsum = (sa + sb) + (sc + sd);
      rsum += __shfl_xor(rsum, 32);
      l_run += rsum;

      // ---- P^T -> packed f16 pairs
      u32 pk[2][8];
#pragma unroll
      for (int p = 0; p < 8; ++p) {
        pk[0][p] = pkrtz_u(s0[2*p], s0[2*p+1]);
        pk[1][p] = pkrtz_u(s1[2*p], s1[2*p+1]);
      }

      // ---- out^T += Vt . P^T  (B-frags via permlane32_swap, distinct operands)
      __builtin_amdgcn_s_setprio(1);
#pragma unroll
      for (int ks = 0; ks < 4; ++ks) {
        const int c = ks >> 1, base = (ks & 1) * 4;
        auto r0 = __builtin_amdgcn_permlane32_swap((int)pk[c][base + 0], (int)pk[c][base + 2], false, false);
        auto r1 = __builtin_amdgcn_permlane32_swap((int)pk[c][base + 1], (int)pk[c][base + 3], false, false);
        u32x4 bw;
        bw[0] = (u32)r0[0];
        bw[1] = (u32)r1[0];
        bw[2] = (u32)r0[1];
        bw[3] = (u32)r1[1];
        const f16x8 pb = __builtin_bit_cast(f16x8, bw);
        const int cs = ((ks * 2 + (hi ? 1 : 0)) ^ sw) * 8;
        const f16x8 va0 = *(const f16x8*)&vb[l31 * 64 + cs];
        const f16x8 va1 = *(const f16x8*)&vb[(32 + l31) * 64 + cs];
        acc0 = __builtin_amdgcn_mfma_f32_32x32x16_f16(va0, pb, acc0, 0, 0, 0);
        acc1 = __builtin_amdgcn_mfma_f32_32x32x16_f16(va1, pb, acc1, 0, 0, 0);
      }
      __builtin_amdgcn_s_setprio(0);
    }

    __syncthreads();
    cur ^= 1;
  }

  // ---- epilogue: normalize, out^T -> LDS transpose (72-pitch) -> store
  _Float16* tr = &smem[0] + wid * 2304;     // 32 rows x 72 per wave (8 waves = 36.9KB)
  const float invl = 1.0f / l_run;
#pragma unroll
  for (int r = 0; r < 16; ++r) {
    const int d = (r & 3) + 8 * (r >> 2) + (hi ? 4 : 0);
    tr[l31 * 72 + d]      = (_Float16)(acc0[r] * invl);
    tr[l31 * 72 + 32 + d] = (_Float16)(acc1[r] * invl);
  }
  __syncthreads();
  if (partial) {
    if (!hi) ps[u * 256 + wid * 32 + l31] = m_run + log2f(l_run);
    _Float16* dst = (u < 416) ? (pO0 + (size_t)u * 16384)
                              : (pO1 + (size_t)(u - 416) * 16384);
#pragma unroll
    for (int cc = 0; cc < 4; ++cc) {
      const int qq = cc * 8 + (lane >> 3), c8 = lane & 7;
      const f16x8 v = *(const f16x8*)&tr[qq * 72 + c8 * 8];
      *(f16x8*)&dst[(wid * 32 + qq) * 64 + c8 * 8] = v;
    }
  } else {
#pragma unroll
    for (int cc = 0; cc < 4; ++cc) {
      const int qq = cc * 8 + (lane >> 3), c8 = lane & 7;
      const f16x8 v = *(const f16x8*)&tr[qq * 72 + c8 * 8];
      *(f16x8*)&Om[(size_t)(q0w + qq) * DMODEL + h * HDIM + c8 * 8] = v;
    }
  }
}

// ---------------------------------------------------------------- combine partials (q >= 768)
__global__ __launch_bounds__(256)
void combine_k(const _Float16* __restrict__ pO0,
               const _Float16* __restrict__ pO1,
               const float* __restrict__ ps,
               _Float16* __restrict__ Om)
{
  const int t  = blockIdx.x * 256 + threadIdx.x;   // 0..425983
  const int d8 = t & 7;
  const int hh = (t >> 3) & 15;
  const int q  = 768 + (t >> 7);
  const int j  = q >> 8;                           // 3..15 (256-row blocks)
  const int qr = q & 255;
  const int parts = PARTS_OF[j];
  const int u0 = hh * 51 + OFF_OF[j];

  float sv[6];
#pragma unroll
  for (int p = 0; p < 6; ++p)
    sv[p] = (p < parts) ? ps[(u0 + p) * 256 + qr] : -1e30f;
  const float S = fmaxf(m3(sv[0], sv[1], sv[2]), m3(sv[3], sv[4], sv[5]));

  float o[8] = {0.f, 0.f, 0.f, 0.f, 0.f, 0.f, 0.f, 0.f};
  float tot = 0.f;
#pragma unroll
  for (int p = 0; p < 6; ++p) {
    if (p < parts) {
      const float w = exp2f(sv[p] - S);
      tot += w;
      const int uu = u0 + p;
      const _Float16* pp = (uu < 416) ? (pO0 + (size_t)uu * 16384)
                                      : (pO1 + (size_t)(uu - 416) * 16384);
      const f16x8 v = *(const f16x8*)&pp[qr * 64 + d8 * 8];
#pragma unroll
      for (int e = 0; e < 8; ++e) o[e] += w * (float)v[e];
    }
  }
  const float inv = 1.0f / tot;
  f16x8 ov;
#pragma unroll
  for (int e = 0; e < 8; ++e) ov[e] = (_Float16)(o[e] * inv);
  *(f16x8*)&Om[(size_t)q * DMODEL + hh * 64 + d8 * 8] = ov;
}

// ---------------------------------------------------------------- launch
extern "C" void kernel_launch(void* const* d_in, const int* in_sizes, int n_in,
                              void* d_out, int out_size, void* d_ws, size_t ws_size,
                              hipStream_t stream)
{
  const float* hs = (const float*)d_in[0];
  const float* ts = (const float*)d_in[1];
  const float* Wq = (const float*)d_in[2];
  const float* bq = (const float*)d_in[3];
  const float* Wk = (const float*)d_in[4];
  const float* bk = (const float*)d_in[5];
  const float* Wv = (const float*)d_in[6];
  const float* bv = (const float*)d_in[7];
  const float* Wo = (const float*)d_in[8];
  float* out = (float*)d_out;

  char* ws = (char*)d_ws;
  const size_t MB = 1024 * 1024;
  _Float16* hsb  = (_Float16*)(ws + 0 * MB);    // [S][D] 8MB (dead after gemm_qkv)
  _Float16* wqb  = (_Float16*)(ws + 8 * MB);    // 2MB    (dead after gemm_qkv)
  _Float16* wkb  = (_Float16*)(ws + 10 * MB);
  _Float16* wvb  = (_Float16*)(ws + 12 * MB);
  _Float16* wob  = (_Float16*)(ws + 14 * MB);   // live until gemm_o
  _Float16* Qb   = (_Float16*)(ws + 16 * MB);
  _Float16* Kb   = (_Float16*)(ws + 24 * MB);
  _Float16* Vtb  = (_Float16*)(ws + 32 * MB);   // [D][S] transposed
  _Float16* attb = (_Float16*)(ws + 40 * MB);
  // attention partial scratch: units 0..415 (32KB each) in dead ws cast region,
  // units 416..815 in d_out (dead until gemm_o overwrites it).
  _Float16* pO0  = (_Float16*)(ws + 0 * MB);            // 416 x 32KB = 13.0MB
  _Float16* pO1  = (_Float16*)d_out;                    // 400 x 32KB = 12.5MB (of 16MB)
  float*    ps   = (float*)   (ws + (size_t)13631488);  // 816 x 1KB = 835KB (< 14MB)

  cast_f32_f16_k<<<dim3(4096), dim3(256), 0, stream>>>(hs, hsb, S_LEN * DMODEL);
  cast4_k<<<dim3(1024, 4), dim3(256), 0, stream>>>(Wq, Wk, Wv, Wo, wqb, wkb, wvb, wob);

  gemm_qkv<<<dim3(3072 / 128, S_LEN / 128), dim3(256), 0, stream>>>(
      hsb, wqb, bq, bk, bv, ts, Qb, Kb, Vtb);

  attn_fwd<<<dim3(864), dim3(512), 0, stream>>>(Qb, Kb, Vtb, attb, pO0, pO1, ps);
  combine_k<<<dim3(1664), dim3(256), 0, stream>>>(pO0, pO1, ps, attb);

  gemm_o<<<dim3(DMODEL / 128, S_LEN / 64), dim3(256), 0, stream>>>(attb, wob, out);
}

// Round 13
// 153.138 us; speedup vs baseline: 2.6575x; 2.6575x over previous
//
#include <hip/hip_runtime.h>

#define S_LEN  4096
#define DMODEL 1024
#define NHEAD  16
#define HDIM   64

typedef float    f32x4  __attribute__((ext_vector_type(4)));
typedef float    f32x16 __attribute__((ext_vector_type(16)));
typedef _Float16 f16x8  __attribute__((ext_vector_type(8)));
typedef _Float16 f16x4v __attribute__((ext_vector_type(4)));
typedef __fp16   fp16x2 __attribute__((ext_vector_type(2)));
typedef unsigned int u32;
typedef u32 u32x4 __attribute__((ext_vector_type(4)));

// ---------------------------------------------------------------- helpers
__device__ __forceinline__ void gl2lds16(const _Float16* g, _Float16* l) {
  __builtin_amdgcn_global_load_lds(
      (const __attribute__((address_space(1))) unsigned int*)g,
      (__attribute__((address_space(3))) unsigned int*)l, 16, 0, 0);
}

__device__ __forceinline__ u32 pkrtz_u(float a, float b) {
  fp16x2 h = __builtin_amdgcn_cvt_pkrtz(a, b);
  return __builtin_bit_cast(u32, h);
}

__device__ __forceinline__ float m3(float a, float b, float c) {
  return fmaxf(fmaxf(a, b), c);   // clang fuses to v_max3_f32
}

// ---------------------------------------------------------------- merged casts
// blocks 0..4095: hs (4M elems). blocks 4096..8191: four 1M weight mats.
__global__ void cast_all_k(const float* __restrict__ hs,
                           const float* __restrict__ a, const float* __restrict__ b,
                           const float* __restrict__ c, const float* __restrict__ d,
                           _Float16* __restrict__ ohs,
                           _Float16* __restrict__ oa, _Float16* __restrict__ ob,
                           _Float16* __restrict__ oc, _Float16* __restrict__ od) {
  const int bid = blockIdx.x;
  const float* in;
  _Float16* out;
  int local;
  if (bid < 4096) {
    in = hs; out = ohs; local = bid;
  } else {
    const int seg = (bid - 4096) >> 10;
    local = (bid - 4096) & 1023;
    in  = seg == 0 ? a  : seg == 1 ? b  : seg == 2 ? c  : d;
    out = seg == 0 ? oa : seg == 1 ? ob : seg == 2 ? oc : od;
  }
  const int i = (local * 256 + threadIdx.x) * 4;
  const float4 v = *(const float4*)(in + i);
  f16x4v o = { (_Float16)v.x, (_Float16)v.y, (_Float16)v.z, (_Float16)v.w };
  *(f16x4v*)(out + i) = o;
}

// ---------------------------------------------------------------- fused QKV GEMM
// 1D grid 768. XCD-chunked: xcd = bid&7 owns n-tiles [xcd*3, xcd*3+3)
// (B-panel 0.75MB -> L2-resident, reused by all 32 m-tiles).
__global__ __launch_bounds__(256)
void gemm_qkv(const _Float16* __restrict__ A,
              const _Float16* __restrict__ Bw,
              const float* __restrict__ bq,
              const float* __restrict__ bk,
              const float* __restrict__ bv,
              const float* __restrict__ ts,
              _Float16* __restrict__ Qb,
              _Float16* __restrict__ Kb,
              _Float16* __restrict__ Vtb)
{
  __shared__ _Float16 lA[128 * 64];
  __shared__ _Float16 lB[128 * 64];

  const int tid  = threadIdx.x;
  const int wid  = tid >> 6;
  const int lane = tid & 63;
  const int l16  = lane & 15;
  const int lg   = lane >> 4;
  const int wr = wid >> 1, wc = wid & 1;
  const int bid = blockIdx.x, xcd = bid & 7, ci = bid >> 3;   // ci 0..95
  const int n0 = (xcd * 3 + ci / 32) * 128;
  const int m0 = (ci & 31) * 128;
  const int K = DMODEL, M = S_LEN;

  const int lrow   = lane >> 3;
  const int gchunk = (lane & 7) ^ lrow;

  f32x4 acc[4][4] = {};

  for (int k0 = 0; k0 < K; k0 += 64) {
#pragma unroll
    for (int it = 0; it < 4; ++it) {
      const int rbase = (it * 4 + wid) * 8;
      gl2lds16(A  + (size_t)(m0 + rbase + lrow) * K + k0 + gchunk * 8, &lA[rbase * 64]);
      gl2lds16(Bw + (size_t)(n0 + rbase + lrow) * K + k0 + gchunk * 8, &lB[rbase * 64]);
    }
    __syncthreads();
#pragma unroll
    for (int kk = 0; kk < 2; ++kk) {
      f16x8 af[4], bfr[4];
#pragma unroll
      for (int mr = 0; mr < 4; ++mr) {
        const int row = wr * 64 + mr * 16 + l16;
        const int ch  = (kk * 4 + lg) ^ (l16 & 7);
        af[mr] = *(const f16x8*)&lA[row * 64 + ch * 8];
      }
#pragma unroll
      for (int nr = 0; nr < 4; ++nr) {
        const int row = wc * 64 + nr * 16 + l16;
        const int ch  = (kk * 4 + lg) ^ (l16 & 7);
        bfr[nr] = *(const f16x8*)&lB[row * 64 + ch * 8];
      }
#pragma unroll
      for (int mr = 0; mr < 4; ++mr)
#pragma unroll
        for (int nr = 0; nr < 4; ++nr)
          acc[mr][nr] = __builtin_amdgcn_mfma_f32_16x16x32_f16(af[mr], bfr[nr], acc[mr][nr], 0, 0, 0);
    }
    __syncthreads();
  }

  if (n0 >= 2048) {           // ---- V: bias + transposed store
    const int dbase = n0 - 2048;
    float bvv[4];
#pragma unroll
    for (int nr = 0; nr < 4; ++nr) bvv[nr] = bv[dbase + wc * 64 + nr * 16 + l16];
#pragma unroll
    for (int mr = 0; mr < 4; ++mr) {
      const int mbase = m0 + wr * 64 + mr * 16 + lg * 4;
#pragma unroll
      for (int nr = 0; nr < 4; ++nr) {
        const int d = dbase + wc * 64 + nr * 16 + l16;
        f16x4v o = { (_Float16)(acc[mr][nr][0] + bvv[nr]),
                     (_Float16)(acc[mr][nr][1] + bvv[nr]),
                     (_Float16)(acc[mr][nr][2] + bvv[nr]),
                     (_Float16)(acc[mr][nr][3] + bvv[nr]) };
        *(f16x4v*)&Vtb[(size_t)d * M + mbase] = o;
      }
    }
  } else {                    // ---- Q or K: bias + CT-RoPE
    _Float16* O = (n0 < 1024) ? Qb : Kb;
    const float* bias = (n0 < 1024) ? bq : bk;
    const int nloc = n0 & 1023;
    float bvv[4];
#pragma unroll
    for (int nr = 0; nr < 4; ++nr) bvv[nr] = bias[nloc + wc * 64 + nr * 16 + l16];
    const float L2T  = 13.287712379549449f / 32.0f;   // log2(10000)/32
    const float inv0 = exp2f(-(float)l16 * L2T);
    const float inv1 = exp2f(-(float)(l16 + 16) * L2T);
#pragma unroll
    for (int mr = 0; mr < 4; ++mr)
#pragma unroll
      for (int r = 0; r < 4; ++r) {
        const int m = m0 + wr * 64 + mr * 16 + lg * 4 + r;
        const float t = ts[m];
        float s0, c0, s1, c1;
        sincosf(t * inv0, &s0, &c0);
        sincosf(t * inv1, &s1, &c1);
        const float p0 = acc[mr][0][r] + bvv[0];
        const float p1 = acc[mr][1][r] + bvv[1];
        const float p2 = acc[mr][2][r] + bvv[2];
        const float p3 = acc[mr][3][r] + bvv[3];
        const size_t base = (size_t)m * DMODEL + nloc + wc * 64 + l16;
        O[base + 0 ] = (_Float16)(p0 * c0 - p2 * s0);
        O[base + 16] = (_Float16)(p1 * c1 - p3 * s1);
        O[base + 32] = (_Float16)(p2 * c0 + p0 * s0);
        O[base + 48] = (_Float16)(p3 * c1 + p1 * s1);
      }
  }
}

// ---------------------------------------------------------------- O-proj GEMM (f32 out)
// 1D grid 512, 64x128 tile. XCD-chunked: xcd owns n-tile xcd (B-panel 256KB
// L2-resident, reused by 64 m-tiles).
__global__ __launch_bounds__(256)
void gemm_o(const _Float16* __restrict__ A,
            const _Float16* __restrict__ Bw,
            float* __restrict__ O)
{
  __shared__ _Float16 lA[64 * 64];
  __shared__ _Float16 lB[128 * 64];

  const int tid  = threadIdx.x;
  const int wid  = tid >> 6;
  const int lane = tid & 63;
  const int l16  = lane & 15;
  const int lg   = lane >> 4;
  const int wr = wid >> 1, wc = wid & 1;
  const int bid = blockIdx.x, xcd = bid & 7, ci = bid >> 3;   // ci 0..63
  const int n0 = xcd * 128;
  const int m0 = ci * 64;
  const int K = DMODEL, N = DMODEL;

  const int lrow   = lane >> 3;
  const int gchunk = (lane & 7) ^ lrow;

  f32x4 acc[2][4] = {};

  for (int k0 = 0; k0 < K; k0 += 64) {
#pragma unroll
    for (int it = 0; it < 2; ++it) {
      const int rbase = (it * 4 + wid) * 8;
      gl2lds16(A + (size_t)(m0 + rbase + lrow) * K + k0 + gchunk * 8, &lA[rbase * 64]);
    }
#pragma unroll
    for (int it = 0; it < 4; ++it) {
      const int rbase = (it * 4 + wid) * 8;
      gl2lds16(Bw + (size_t)(n0 + rbase + lrow) * K + k0 + gchunk * 8, &lB[rbase * 64]);
    }
    __syncthreads();
#pragma unroll
    for (int kk = 0; kk < 2; ++kk) {
      f16x8 af[2], bfr[4];
#pragma unroll
      for (int mr = 0; mr < 2; ++mr) {
        const int row = wr * 32 + mr * 16 + l16;
        const int ch  = (kk * 4 + lg) ^ (l16 & 7);
        af[mr] = *(const f16x8*)&lA[row * 64 + ch * 8];
      }
#pragma unroll
      for (int nr = 0; nr < 4; ++nr) {
        const int row = wc * 64 + nr * 16 + l16;
        const int ch  = (kk * 4 + lg) ^ (l16 & 7);
        bfr[nr] = *(const f16x8*)&lB[row * 64 + ch * 8];
      }
#pragma unroll
      for (int mr = 0; mr < 2; ++mr)
#pragma unroll
        for (int nr = 0; nr < 4; ++nr)
          acc[mr][nr] = __builtin_amdgcn_mfma_f32_16x16x32_f16(af[mr], bfr[nr], acc[mr][nr], 0, 0, 0);
    }
    __syncthreads();
  }

#pragma unroll
  for (int mr = 0; mr < 2; ++mr)
#pragma unroll
    for (int r = 0; r < 4; ++r) {
      const int m = m0 + wr * 32 + mr * 16 + lg * 4 + r;
#pragma unroll
      for (int nr = 0; nr < 4; ++nr) {
        const int n = n0 + wc * 64 + nr * 16 + l16;
        O[(size_t)m * N + n] = acc[mr][nr][r];
      }
    }
}

// ---------------------------------------------------------------- flash attention v9 (reverted, known-good)
// 1280 blocks x 256 thr (4 waves x 32 q = 128 q-rows/block).
// parts(jb) = jb/8 + 1: jb 24-31 ->4, 16-23 ->3, 8-15 ->2, 0-7 ->1.
__device__ __forceinline__ void stage_tiles(const _Float16* __restrict__ Km,
                                            const _Float16* __restrict__ Vt,
                                            _Float16* kdst, _Float16* vdst,
                                            int kv0, int h, int wid, int lane) {
#pragma unroll
  for (int j8 = 0; j8 < 2; ++j8) {
    const int rb  = wid * 16 + j8 * 8;       // wave-uniform row base (4 waves cover 64)
    const int row = rb + (lane >> 3);
    const int g   = (lane & 7) ^ (row & 7);  // pre-swizzled source chunk
    gl2lds16(Km + (size_t)(kv0 + row) * DMODEL + h * HDIM + g * 8, kdst + rb * 64);
    gl2lds16(Vt + (size_t)(h * HDIM + row) * S_LEN + kv0 + g * 8, vdst + rb * 64);
  }
}

__device__ __forceinline__ int part_off(int jb) {
  if (jb >= 24) return 40 + (jb - 24) * 4;
  if (jb >= 16) return 16 + (jb - 16) * 3;
  return (jb - 8) * 2;
}

__global__ __launch_bounds__(256, 4)
void attn_fwd(const _Float16* __restrict__ Q,
              const _Float16* __restrict__ Km,
              const _Float16* __restrict__ Vt,
              _Float16* __restrict__ Om,
              _Float16* __restrict__ pO0,
              _Float16* __restrict__ pO1,
              float* __restrict__ ps)
{
  __shared__ __align__(16) _Float16 smem[2][2][64 * 64];   // 32KB

  const int tid  = threadIdx.x;
  const int wid  = tid >> 6, lane = tid & 63;
  const int l31  = lane & 31;
  const bool hi  = (lane & 32) != 0;
  const int flat = blockIdx.x, xcd = flat & 7, idx = flat >> 3;  // idx 0..159
  const int h    = xcd * 2 + (idx & 1);
  const int slot = idx >> 1;                  // 0..79, ascending = heaviest first
  int jb, part, parts;
  if (slot < 32)      { jb = 31 - (slot >> 2);              part = slot & 3;  parts = 4; }
  else if (slot < 56) { const int t = slot - 32; jb = 23 - t / 3; part = t % 3; parts = 3; }
  else if (slot < 72) { const int t = slot - 56; jb = 15 - (t >> 1); part = t & 1; parts = 2; }
  else                { jb = 79 - slot;                     part = 0;        parts = 1; }
  const int nt  = 2 * jb + 2;
  const int kt0 = (nt * part) / parts, kt1 = (nt * (part + 1)) / parts;
  const bool partial = parts > 1;
  const int u = partial ? (h * 72 + part_off(jb) + part) : 0;
  const int q0w = jb * 128 + wid * 32;
  const int sw  = l31 & 7;                    // LDS read swizzle

  // Q B-fragments, pre-scaled by (1/sqrt(64))*log2(e)
  f16x8 qf[4];
  {
    const float qs = 0.18033688f;
    const size_t qbase = (size_t)(q0w + l31) * DMODEL + h * HDIM + (hi ? 8 : 0);
#pragma unroll
    for (int ks = 0; ks < 4; ++ks) {
      f16x8 t = *(const f16x8*)&Q[qbase + ks * 16];
#pragma unroll
      for (int e = 0; e < 8; ++e) qf[ks][e] = (_Float16)((float)t[e] * qs);
    }
  }

  f32x16 acc0, acc1;
#pragma unroll
  for (int r = 0; r < 16; ++r) { acc0[r] = 0.f; acc1[r] = 0.f; }
  float m_run = 0.f, l_run = 0.f;   // scores tracked as S - m_run; m starts 0

  stage_tiles(Km, Vt, &smem[0][0][0], &smem[0][1][0], kt0 * 64, h, wid, lane);
  __syncthreads();
  int cur = 0;

  for (int kt = kt0; kt < kt1; ++kt) {
    if (kt + 1 < kt1)
      stage_tiles(Km, Vt, &smem[cur ^ 1][0][0], &smem[cur ^ 1][1][0],
                  (kt + 1) * 64, h, wid, lane);

    const int kv0 = kt * 64;
    if (kv0 <= q0w + 31) {           // wave has at least one unmasked column
      const _Float16* kb = &smem[cur][0][0];
      const _Float16* vb = &smem[cur][1][0];

      // ---- S^T - m_run = K . Q^T + (-m_run)  (rows = kv, cols = q)
      f32x16 s0, s1;
#pragma unroll
      for (int r = 0; r < 16; ++r) { s0[r] = -m_run; s1[r] = -m_run; }
      __builtin_amdgcn_s_setprio(1);
#pragma unroll
      for (int ks = 0; ks < 4; ++ks) {
        const int cs = ((ks * 2 + (hi ? 1 : 0)) ^ sw) * 8;
        const f16x8 ka0 = *(const f16x8*)&kb[l31 * 64 + cs];
        const f16x8 ka1 = *(const f16x8*)&kb[(32 + l31) * 64 + cs];
        s0 = __builtin_amdgcn_mfma_f32_32x32x16_f16(ka0, qf[ks], s0, 0, 0, 0);
        s1 = __builtin_amdgcn_mfma_f32_32x32x16_f16(ka1, qf[ks], s1, 0, 0, 0);
      }
      __builtin_amdgcn_s_setprio(0);

      if (kv0 + 63 > q0w) {          // diagonal tile: causal mask
        const int q = q0w + l31;
#pragma unroll
        for (int r = 0; r < 16; ++r) {
          const int kvr = kv0 + (r & 3) + 8 * (r >> 2) + (hi ? 4 : 0);
          if (kvr > q)      s0[r] = -1e30f;
          if (kvr + 32 > q) s1[r] = -1e30f;
        }
      }

      // ---- online softmax (exp2 domain), lane-local rows, defer-max
      float t10[10];
#pragma unroll
      for (int p = 0; p < 5; ++p) {
        t10[p]     = m3(s0[3*p], s0[3*p+1], s0[3*p+2]);
        t10[5 + p] = m3(s1[3*p], s1[3*p+1], s1[3*p+2]);
      }
      float u0 = m3(t10[0], t10[1], t10[2]);
      float u1 = m3(t10[3], t10[4], s0[15]);
      float u2 = m3(t10[5], t10[6], t10[7]);
      float u3 = m3(t10[8], t10[9], s1[15]);
      float pm = fmaxf(m3(u0, u1, u2), u3);
      pm = fmaxf(pm, __shfl_xor(pm, 32));

      if (!__all(pm <= 10.f)) {      // rescale (rare after first tile)
        m_run += pm;
        const float scl = exp2f(-pm);
        l_run *= scl;
#pragma unroll
        for (int r = 0; r < 16; ++r) { acc0[r] *= scl; acc1[r] *= scl; }
#pragma unroll
        for (int r = 0; r < 16; ++r) { s0[r] -= pm; s1[r] -= pm; }
      }

      float sa = 0.f, sb = 0.f, sc = 0.f, sd = 0.f;
#pragma unroll
      for (int r = 0; r < 16; r += 2) {
        s0[r]   = exp2f(s0[r]);
        s0[r+1] = exp2f(s0[r+1]);
        s1[r]   = exp2f(s1[r]);
        s1[r+1] = exp2f(s1[r+1]);
        sa += s0[r]; sb += s0[r+1]; sc += s1[r]; sd += s1[r+1];
      }
      float rsum = (sa + sb) + (sc + sd);
      rsum += __shfl_xor(rsum, 32);
      l_run += rsum;

      // ---- P^T -> packed f16 pairs
      u32 pk[2][8];
#pragma unroll
      for (int p = 0; p < 8; ++p) {
        pk[0][p] = pkrtz_u(s0[2*p], s0[2*p+1]);
        pk[1][p] = pkrtz_u(s1[2*p], s1[2*p+1]);
      }

      // ---- out^T += Vt . P^T  (B-frags via permlane32_swap, distinct operands)
      __builtin_amdgcn_s_setprio(1);
#pragma unroll
      for (int ks = 0; ks < 4; ++ks) {
        const int c = ks >> 1, base = (ks & 1) * 4;
        auto r0 = __builtin_amdgcn_permlane32_swap((int)pk[c][base + 0], (int)pk[c][base + 2], false, false);
        auto r1 = __builtin_amdgcn_permlane32_swap((int)pk[c][base + 1], (int)pk[c][base + 3], false, false);
        u32x4 bw;
        bw[0] = (u32)r0[0];
        bw[1] = (u32)r1[0];
        bw[2] = (u32)r0[1];
        bw[3] = (u32)r1[1];
        const f16x8 pb = __builtin_bit_cast(f16x8, bw);
        const int cs = ((ks * 2 + (hi ? 1 : 0)) ^ sw) * 8;
        const f16x8 va0 = *(const f16x8*)&vb[l31 * 64 + cs];
        const f16x8 va1 = *(const f16x8*)&vb[(32 + l31) * 64 + cs];
        acc0 = __builtin_amdgcn_mfma_f32_32x32x16_f16(va0, pb, acc0, 0, 0, 0);
        acc1 = __builtin_amdgcn_mfma_f32_32x32x16_f16(va1, pb, acc1, 0, 0, 0);
      }
      __builtin_amdgcn_s_setprio(0);
    }

    __syncthreads();
    cur ^= 1;
  }

  // ---- epilogue: normalize, out^T -> LDS transpose (72-pitch) -> store
  _Float16* tr = &smem[0][0][0] + wid * 2304;     // 32 rows x 72 per wave
  const float invl = 1.0f / l_run;
#pragma unroll
  for (int r = 0; r < 16; ++r) {
    const int d = (r & 3) + 8 * (r >> 2) + (hi ? 4 : 0);
    tr[l31 * 72 + d]      = (_Float16)(acc0[r] * invl);
    tr[l31 * 72 + 32 + d] = (_Float16)(acc1[r] * invl);
  }
  __syncthreads();
  if (partial) {
    if (!hi) ps[u * 128 + wid * 32 + l31] = m_run + log2f(l_run);
    _Float16* dst = (u < 832) ? (pO0 + (size_t)u * 8192)
                              : (pO1 + (size_t)(u - 832) * 8192);
#pragma unroll
    for (int cc = 0; cc < 4; ++cc) {
      const int qq = cc * 8 + (lane >> 3), c8 = lane & 7;
      const f16x8 v = *(const f16x8*)&tr[qq * 72 + c8 * 8];
      *(f16x8*)&dst[(wid * 32 + qq) * 64 + c8 * 8] = v;
    }
  } else {
#pragma unroll
    for (int cc = 0; cc < 4; ++cc) {
      const int qq = cc * 8 + (lane >> 3), c8 = lane & 7;
      const f16x8 v = *(const f16x8*)&tr[qq * 72 + c8 * 8];
      *(f16x8*)&Om[(size_t)(q0w + qq) * DMODEL + h * HDIM + c8 * 8] = v;
    }
  }
}

// ---------------------------------------------------------------- combine partials (q >= 1024)
__global__ __launch_bounds__(256)
void combine_k(const _Float16* __restrict__ pO0,
               const _Float16* __restrict__ pO1,
               const float* __restrict__ ps,
               _Float16* __restrict__ Om)
{
  const int t  = blockIdx.x * 256 + threadIdx.x;   // 0..393215
  const int d8 = t & 7;
  const int hh = (t >> 3) & 15;
  const int q  = 1024 + (t >> 7);
  const int j  = q >> 7;                           // 8..31 (128-row blocks)
  const int qr = q & 127;
  const int parts = (j >= 24) ? 4 : (j >= 16) ? 3 : 2;
  const int off   = (j >= 24) ? 40 + (j - 24) * 4
                  : (j >= 16) ? 16 + (j - 16) * 3
                  :             (j - 8) * 2;
  const int u0 = hh * 72 + off;

  float sv[4];
#pragma unroll
  for (int p = 0; p < 4; ++p)
    sv[p] = (p < parts) ? ps[(u0 + p) * 128 + qr] : -1e30f;
  const float S = fmaxf(fmaxf(sv[0], sv[1]), fmaxf(sv[2], sv[3]));

  float o[8] = {0.f, 0.f, 0.f, 0.f, 0.f, 0.f, 0.f, 0.f};
  float tot = 0.f;
#pragma unroll
  for (int p = 0; p < 4; ++p) {
    if (p < parts) {
      const float w = exp2f(sv[p] - S);
      tot += w;
      const int uu = u0 + p;
      const _Float16* pp = (uu < 832) ? (pO0 + (size_t)uu * 8192)
                                      : (pO1 + (size_t)(uu - 832) * 8192);
      const f16x8 v = *(const f16x8*)&pp[qr * 64 + d8 * 8];
#pragma unroll
      for (int e = 0; e < 8; ++e) o[e] += w * (float)v[e];
    }
  }
  const float inv = 1.0f / tot;
  f16x8 ov;
#pragma unroll
  for (int e = 0; e < 8; ++e) ov[e] = (_Float16)(o[e] * inv);
  *(f16x8*)&Om[(size_t)q * DMODEL + hh * 64 + d8 * 8] = ov;
}

// ---------------------------------------------------------------- launch
extern "C" void kernel_launch(void* const* d_in, const int* in_sizes, int n_in,
                              void* d_out, int out_size, void* d_ws, size_t ws_size,
                              hipStream_t stream)
{
  const float* hs = (const float*)d_in[0];
  const float* ts = (const float*)d_in[1];
  const float* Wq = (const float*)d_in[2];
  const float* bq = (const float*)d_in[3];
  const float* Wk = (const float*)d_in[4];
  const float* bk = (const float*)d_in[5];
  const float* Wv = (const float*)d_in[6];
  const float* bv = (const float*)d_in[7];
  const float* Wo = (const float*)d_in[8];
  float* out = (float*)d_out;

  char* ws = (char*)d_ws;
  const size_t MB = 1024 * 1024;
  _Float16* hsb  = (_Float16*)(ws + 0 * MB);    // [S][D] 8MB (dead after gemm_qkv)
  _Float16* wqb  = (_Float16*)(ws + 8 * MB);    // 2MB    (dead after gemm_qkv)
  _Float16* wkb  = (_Float16*)(ws + 10 * MB);
  _Float16* wvb  = (_Float16*)(ws + 12 * MB);
  _Float16* wob  = (_Float16*)(ws + 14 * MB);   // live until gemm_o
  _Float16* Qb   = (_Float16*)(ws + 16 * MB);
  _Float16* Kb   = (_Float16*)(ws + 24 * MB);
  _Float16* Vtb  = (_Float16*)(ws + 32 * MB);   // [D][S] transposed
  _Float16* attb = (_Float16*)(ws + 40 * MB);
  // attention partial scratch: units 0..831 in dead ws cast region,
  // units 832..1151 in d_out (dead until gemm_o overwrites it).
  _Float16* pO0  = (_Float16*)(ws + 0 * MB);            // 832 x 16KB = 13.0MB
  _Float16* pO1  = (_Float16*)d_out;                    // 320 x 16KB = 5.0MB (of 16MB)
  float*    ps   = (float*)   (ws + (size_t)13631488);  // 1152 x 512B = 590KB (< 14MB)

  cast_all_k<<<dim3(8192), dim3(256), 0, stream>>>(hs, Wq, Wk, Wv, Wo,
                                                   hsb, wqb, wkb, wvb, wob);

  gemm_qkv<<<dim3(768), dim3(256), 0, stream>>>(
      hsb, wqb, bq, bk, bv, ts, Qb, Kb, Vtb);

  attn_fwd<<<dim3(1280), dim3(256), 0, stream>>>(Qb, Kb, Vtb, attb, pO0, pO1, ps);
  combine_k<<<dim3(1536), dim3(256), 0, stream>>>(pO0, pO1, ps, attb);

  gemm_o<<<dim3(512), dim3(256), 0, stream>>>(attb, wob, out);
}

// Round 14
// 137.201 us; speedup vs baseline: 2.9662x; 1.1162x over previous
//
#include <hip/hip_runtime.h>

#define S_LEN  4096
#define DMODEL 1024
#define NHEAD  16
#define HDIM   64

typedef float    f32x4  __attribute__((ext_vector_type(4)));
typedef float    f32x16 __attribute__((ext_vector_type(16)));
typedef _Float16 f16x8  __attribute__((ext_vector_type(8)));
typedef _Float16 f16x4v __attribute__((ext_vector_type(4)));
typedef __fp16   fp16x2 __attribute__((ext_vector_type(2)));
typedef unsigned int u32;
typedef u32 u32x4 __attribute__((ext_vector_type(4)));

// ---------------------------------------------------------------- helpers
__device__ __forceinline__ void gl2lds16(const _Float16* g, _Float16* l) {
  __builtin_amdgcn_global_load_lds(
      (const __attribute__((address_space(1))) unsigned int*)g,
      (__attribute__((address_space(3))) unsigned int*)l, 16, 0, 0);
}

__device__ __forceinline__ u32 pkrtz_u(float a, float b) {
  fp16x2 h = __builtin_amdgcn_cvt_pkrtz(a, b);
  return __builtin_bit_cast(u32, h);
}

__device__ __forceinline__ float m3(float a, float b, float c) {
  return fmaxf(fmaxf(a, b), c);   // clang fuses to v_max3_f32
}

// native transcendentals (bare v_exp/v_log/v_rcp, no libm guard code)
__device__ __forceinline__ float ex2(float x) { return __builtin_amdgcn_exp2f(x); }
__device__ __forceinline__ float lg2(float x) { return __builtin_amdgcn_logf(x); }
__device__ __forceinline__ float rcp(float x) { return __builtin_amdgcn_rcpf(x); }

// ---------------------------------------------------------------- merged casts
__global__ void cast_all_k(const float* __restrict__ hs,
                           const float* __restrict__ a, const float* __restrict__ b,
                           const float* __restrict__ c, const float* __restrict__ d,
                           _Float16* __restrict__ ohs,
                           _Float16* __restrict__ oa, _Float16* __restrict__ ob,
                           _Float16* __restrict__ oc, _Float16* __restrict__ od) {
  const int bid = blockIdx.x;
  const float* in;
  _Float16* out;
  int local;
  if (bid < 4096) {
    in = hs; out = ohs; local = bid;
  } else {
    const int seg = (bid - 4096) >> 10;
    local = (bid - 4096) & 1023;
    in  = seg == 0 ? a  : seg == 1 ? b  : seg == 2 ? c  : d;
    out = seg == 0 ? oa : seg == 1 ? ob : seg == 2 ? oc : od;
  }
  const int i = (local * 256 + threadIdx.x) * 4;
  const float4 v = *(const float4*)(in + i);
  f16x4v o = { (_Float16)v.x, (_Float16)v.y, (_Float16)v.z, (_Float16)v.w };
  *(f16x4v*)(out + i) = o;
}

// ---------------------------------------------------------------- fused QKV GEMM
// 1D grid 768, XCD-chunked (xcd owns 3 n-tiles; B-panel L2-resident).
__global__ __launch_bounds__(256)
void gemm_qkv(const _Float16* __restrict__ A,
              const _Float16* __restrict__ Bw,
              const float* __restrict__ bq,
              const float* __restrict__ bk,
              const float* __restrict__ bv,
              const float* __restrict__ ts,
              _Float16* __restrict__ Qb,
              _Float16* __restrict__ Kb,
              _Float16* __restrict__ Vtb)
{
  __shared__ _Float16 lA[128 * 64];
  __shared__ _Float16 lB[128 * 64];

  const int tid  = threadIdx.x;
  const int wid  = tid >> 6;
  const int lane = tid & 63;
  const int l16  = lane & 15;
  const int lg   = lane >> 4;
  const int wr = wid >> 1, wc = wid & 1;
  const int bid = blockIdx.x, xcd = bid & 7, ci = bid >> 3;   // ci 0..95
  const int n0 = (xcd * 3 + ci / 32) * 128;
  const int m0 = (ci & 31) * 128;
  const int K = DMODEL, M = S_LEN;

  const int lrow   = lane >> 3;
  const int gchunk = (lane & 7) ^ lrow;

  f32x4 acc[4][4] = {};

  for (int k0 = 0; k0 < K; k0 += 64) {
#pragma unroll
    for (int it = 0; it < 4; ++it) {
      const int rbase = (it * 4 + wid) * 8;
      gl2lds16(A  + (size_t)(m0 + rbase + lrow) * K + k0 + gchunk * 8, &lA[rbase * 64]);
      gl2lds16(Bw + (size_t)(n0 + rbase + lrow) * K + k0 + gchunk * 8, &lB[rbase * 64]);
    }
    __syncthreads();
#pragma unroll
    for (int kk = 0; kk < 2; ++kk) {
      f16x8 af[4], bfr[4];
#pragma unroll
      for (int mr = 0; mr < 4; ++mr) {
        const int row = wr * 64 + mr * 16 + l16;
        const int ch  = (kk * 4 + lg) ^ (l16 & 7);
        af[mr] = *(const f16x8*)&lA[row * 64 + ch * 8];
      }
#pragma unroll
      for (int nr = 0; nr < 4; ++nr) {
        const int row = wc * 64 + nr * 16 + l16;
        const int ch  = (kk * 4 + lg) ^ (l16 & 7);
        bfr[nr] = *(const f16x8*)&lB[row * 64 + ch * 8];
      }
#pragma unroll
      for (int mr = 0; mr < 4; ++mr)
#pragma unroll
        for (int nr = 0; nr < 4; ++nr)
          acc[mr][nr] = __builtin_amdgcn_mfma_f32_16x16x32_f16(af[mr], bfr[nr], acc[mr][nr], 0, 0, 0);
    }
    __syncthreads();
  }

  if (n0 >= 2048) {           // ---- V: bias + transposed store
    const int dbase = n0 - 2048;
    float bvv[4];
#pragma unroll
    for (int nr = 0; nr < 4; ++nr) bvv[nr] = bv[dbase + wc * 64 + nr * 16 + l16];
#pragma unroll
    for (int mr = 0; mr < 4; ++mr) {
      const int mbase = m0 + wr * 64 + mr * 16 + lg * 4;
#pragma unroll
      for (int nr = 0; nr < 4; ++nr) {
        const int d = dbase + wc * 64 + nr * 16 + l16;
        f16x4v o = { (_Float16)(acc[mr][nr][0] + bvv[nr]),
                     (_Float16)(acc[mr][nr][1] + bvv[nr]),
                     (_Float16)(acc[mr][nr][2] + bvv[nr]),
                     (_Float16)(acc[mr][nr][3] + bvv[nr]) };
        *(f16x4v*)&Vtb[(size_t)d * M + mbase] = o;
      }
    }
  } else {                    // ---- Q or K: bias + CT-RoPE (native sin/cos, revolutions)
    _Float16* O = (n0 < 1024) ? Qb : Kb;
    const float* bias = (n0 < 1024) ? bq : bk;
    const int nloc = n0 & 1023;
    float bvv[4];
#pragma unroll
    for (int nr = 0; nr < 4; ++nr) bvv[nr] = bias[nloc + wc * 64 + nr * 16 + l16];
    const float L2T  = 13.287712379549449f / 32.0f;   // log2(10000)/32
    const float R2PI = 0.15915494309189535f;          // 1/(2*pi)
    const float inv0 = ex2(-(float)l16 * L2T) * R2PI;         // rev per unit t
    const float inv1 = ex2(-(float)(l16 + 16) * L2T) * R2PI;
#pragma unroll
    for (int mr = 0; mr < 4; ++mr)
#pragma unroll
      for (int r = 0; r < 4; ++r) {
        const int m = m0 + wr * 64 + mr * 16 + lg * 4 + r;
        const float t = ts[m];
        const float a0 = __builtin_amdgcn_fractf(t * inv0);
        const float a1 = __builtin_amdgcn_fractf(t * inv1);
        const float s0 = __builtin_amdgcn_sinf(a0), c0 = __builtin_amdgcn_cosf(a0);
        const float s1 = __builtin_amdgcn_sinf(a1), c1 = __builtin_amdgcn_cosf(a1);
        const float p0 = acc[mr][0][r] + bvv[0];
        const float p1 = acc[mr][1][r] + bvv[1];
        const float p2 = acc[mr][2][r] + bvv[2];
        const float p3 = acc[mr][3][r] + bvv[3];
        const size_t base = (size_t)m * DMODEL + nloc + wc * 64 + l16;
        O[base + 0 ] = (_Float16)(p0 * c0 - p2 * s0);
        O[base + 16] = (_Float16)(p1 * c1 - p3 * s1);
        O[base + 32] = (_Float16)(p2 * c0 + p0 * s0);
        O[base + 48] = (_Float16)(p3 * c1 + p1 * s1);
      }
  }
}

// ---------------------------------------------------------------- O-proj GEMM (f32 out)
// 1D grid 512, 64x128 tile, XCD-chunked.
__global__ __launch_bounds__(256)
void gemm_o(const _Float16* __restrict__ A,
            const _Float16* __restrict__ Bw,
            float* __restrict__ O)
{
  __shared__ _Float16 lA[64 * 64];
  __shared__ _Float16 lB[128 * 64];

  const int tid  = threadIdx.x;
  const int wid  = tid >> 6;
  const int lane = tid & 63;
  const int l16  = lane & 15;
  const int lg   = lane >> 4;
  const int wr = wid >> 1, wc = wid & 1;
  const int bid = blockIdx.x, xcd = bid & 7, ci = bid >> 3;   // ci 0..63
  const int n0 = xcd * 128;
  const int m0 = ci * 64;
  const int K = DMODEL, N = DMODEL;

  const int lrow   = lane >> 3;
  const int gchunk = (lane & 7) ^ lrow;

  f32x4 acc[2][4] = {};

  for (int k0 = 0; k0 < K; k0 += 64) {
#pragma unroll
    for (int it = 0; it < 2; ++it) {
      const int rbase = (it * 4 + wid) * 8;
      gl2lds16(A + (size_t)(m0 + rbase + lrow) * K + k0 + gchunk * 8, &lA[rbase * 64]);
    }
#pragma unroll
    for (int it = 0; it < 4; ++it) {
      const int rbase = (it * 4 + wid) * 8;
      gl2lds16(Bw + (size_t)(n0 + rbase + lrow) * K + k0 + gchunk * 8, &lB[rbase * 64]);
    }
    __syncthreads();
#pragma unroll
    for (int kk = 0; kk < 2; ++kk) {
      f16x8 af[2], bfr[4];
#pragma unroll
      for (int mr = 0; mr < 2; ++mr) {
        const int row = wr * 32 + mr * 16 + l16;
        const int ch  = (kk * 4 + lg) ^ (l16 & 7);
        af[mr] = *(const f16x8*)&lA[row * 64 + ch * 8];
      }
#pragma unroll
      for (int nr = 0; nr < 4; ++nr) {
        const int row = wc * 64 + nr * 16 + l16;
        const int ch  = (kk * 4 + lg) ^ (l16 & 7);
        bfr[nr] = *(const f16x8*)&lB[row * 64 + ch * 8];
      }
#pragma unroll
      for (int mr = 0; mr < 2; ++mr)
#pragma unroll
        for (int nr = 0; nr < 4; ++nr)
          acc[mr][nr] = __builtin_amdgcn_mfma_f32_16x16x32_f16(af[mr], bfr[nr], acc[mr][nr], 0, 0, 0);
    }
    __syncthreads();
  }

#pragma unroll
  for (int mr = 0; mr < 2; ++mr)
#pragma unroll
    for (int r = 0; r < 4; ++r) {
      const int m = m0 + wr * 32 + mr * 16 + lg * 4 + r;
#pragma unroll
      for (int nr = 0; nr < 4; ++nr) {
        const int n = n0 + wc * 64 + nr * 16 + l16;
        O[(size_t)m * N + n] = acc[mr][nr][r];
      }
    }
}

// ---------------------------------------------------------------- flash attention v9 + native exp2
__device__ __forceinline__ void stage_tiles(const _Float16* __restrict__ Km,
                                            const _Float16* __restrict__ Vt,
                                            _Float16* kdst, _Float16* vdst,
                                            int kv0, int h, int wid, int lane) {
#pragma unroll
  for (int j8 = 0; j8 < 2; ++j8) {
    const int rb  = wid * 16 + j8 * 8;       // wave-uniform row base (4 waves cover 64)
    const int row = rb + (lane >> 3);
    const int g   = (lane & 7) ^ (row & 7);  // pre-swizzled source chunk
    gl2lds16(Km + (size_t)(kv0 + row) * DMODEL + h * HDIM + g * 8, kdst + rb * 64);
    gl2lds16(Vt + (size_t)(h * HDIM + row) * S_LEN + kv0 + g * 8, vdst + rb * 64);
  }
}

__device__ __forceinline__ int part_off(int jb) {
  if (jb >= 24) return 40 + (jb - 24) * 4;
  if (jb >= 16) return 16 + (jb - 16) * 3;
  return (jb - 8) * 2;
}

__global__ __launch_bounds__(256, 4)
void attn_fwd(const _Float16* __restrict__ Q,
              const _Float16* __restrict__ Km,
              const _Float16* __restrict__ Vt,
              _Float16* __restrict__ Om,
              _Float16* __restrict__ pO0,
              _Float16* __restrict__ pO1,
              float* __restrict__ ps)
{
  __shared__ __align__(16) _Float16 smem[2][2][64 * 64];   // 32KB

  const int tid  = threadIdx.x;
  const int wid  = tid >> 6, lane = tid & 63;
  const int l31  = lane & 31;
  const bool hi  = (lane & 32) != 0;
  const int flat = blockIdx.x, xcd = flat & 7, idx = flat >> 3;  // idx 0..159
  const int h    = xcd * 2 + (idx & 1);
  const int slot = idx >> 1;                  // 0..79, ascending = heaviest first
  int jb, part, parts;
  if (slot < 32)      { jb = 31 - (slot >> 2);              part = slot & 3;  parts = 4; }
  else if (slot < 56) { const int t = slot - 32; jb = 23 - t / 3; part = t % 3; parts = 3; }
  else if (slot < 72) { const int t = slot - 56; jb = 15 - (t >> 1); part = t & 1; parts = 2; }
  else                { jb = 79 - slot;                     part = 0;        parts = 1; }
  const int nt  = 2 * jb + 2;
  const int kt0 = (nt * part) / parts, kt1 = (nt * (part + 1)) / parts;
  const bool partial = parts > 1;
  const int u = partial ? (h * 72 + part_off(jb) + part) : 0;
  const int q0w = jb * 128 + wid * 32;
  const int sw  = l31 & 7;                    // LDS read swizzle

  // Q B-fragments, pre-scaled by (1/sqrt(64))*log2(e)
  f16x8 qf[4];
  {
    const float qs = 0.18033688f;
    const size_t qbase = (size_t)(q0w + l31) * DMODEL + h * HDIM + (hi ? 8 : 0);
#pragma unroll
    for (int ks = 0; ks < 4; ++ks) {
      f16x8 t = *(const f16x8*)&Q[qbase + ks * 16];
#pragma unroll
      for (int e = 0; e < 8; ++e) qf[ks][e] = (_Float16)((float)t[e] * qs);
    }
  }

  f32x16 acc0, acc1;
#pragma unroll
  for (int r = 0; r < 16; ++r) { acc0[r] = 0.f; acc1[r] = 0.f; }
  float m_run = 0.f, l_run = 0.f;   // scores tracked as S - m_run; m starts 0

  stage_tiles(Km, Vt, &smem[0][0][0], &smem[0][1][0], kt0 * 64, h, wid, lane);
  __syncthreads();
  int cur = 0;

  for (int kt = kt0; kt < kt1; ++kt) {
    if (kt + 1 < kt1)
      stage_tiles(Km, Vt, &smem[cur ^ 1][0][0], &smem[cur ^ 1][1][0],
                  (kt + 1) * 64, h, wid, lane);

    const int kv0 = kt * 64;
    if (kv0 <= q0w + 31) {           // wave has at least one unmasked column
      const _Float16* kb = &smem[cur][0][0];
      const _Float16* vb = &smem[cur][1][0];

      // ---- S^T - m_run = K . Q^T + (-m_run)  (rows = kv, cols = q)
      f32x16 s0, s1;
#pragma unroll
      for (int r = 0; r < 16; ++r) { s0[r] = -m_run; s1[r] = -m_run; }
      __builtin_amdgcn_s_setprio(1);
#pragma unroll
      for (int ks = 0; ks < 4; ++ks) {
        const int cs = ((ks * 2 + (hi ? 1 : 0)) ^ sw) * 8;
        const f16x8 ka0 = *(const f16x8*)&kb[l31 * 64 + cs];
        const f16x8 ka1 = *(const f16x8*)&kb[(32 + l31) * 64 + cs];
        s0 = __builtin_amdgcn_mfma_f32_32x32x16_f16(ka0, qf[ks], s0, 0, 0, 0);
        s1 = __builtin_amdgcn_mfma_f32_32x32x16_f16(ka1, qf[ks], s1, 0, 0, 0);
      }
      __builtin_amdgcn_s_setprio(0);

      if (kv0 + 63 > q0w) {          // diagonal tile: causal mask
        const int q = q0w + l31;
#pragma unroll
        for (int r = 0; r < 16; ++r) {
          const int kvr = kv0 + (r & 3) + 8 * (r >> 2) + (hi ? 4 : 0);
          if (kvr > q)      s0[r] = -1e30f;
          if (kvr + 32 > q) s1[r] = -1e30f;
        }
      }

      // ---- online softmax (exp2 domain), lane-local rows, defer-max
      float t10[10];
#pragma unroll
      for (int p = 0; p < 5; ++p) {
        t10[p]     = m3(s0[3*p], s0[3*p+1], s0[3*p+2]);
        t10[5 + p] = m3(s1[3*p], s1[3*p+1], s1[3*p+2]);
      }
      float u0 = m3(t10[0], t10[1], t10[2]);
      float u1 = m3(t10[3], t10[4], s0[15]);
      float u2 = m3(t10[5], t10[6], t10[7]);
      float u3 = m3(t10[8], t10[9], s1[15]);
      float pm = fmaxf(m3(u0, u1, u2), u3);
      pm = fmaxf(pm, __shfl_xor(pm, 32));

      if (!__all(pm <= 10.f)) {      // rescale (rare after first tile)
        m_run += pm;
        const float scl = ex2(-pm);
        l_run *= scl;
#pragma unroll
        for (int r = 0; r < 16; ++r) { acc0[r] *= scl; acc1[r] *= scl; }
#pragma unroll
        for (int r = 0; r < 16; ++r) { s0[r] -= pm; s1[r] -= pm; }
      }

      float sa = 0.f, sb = 0.f, sc = 0.f, sd = 0.f;
#pragma unroll
      for (int r = 0; r < 16; r += 2) {
        s0[r]   = ex2(s0[r]);
        s0[r+1] = ex2(s0[r+1]);
        s1[r]   = ex2(s1[r]);
        s1[r+1] = ex2(s1[r+1]);
        sa += s0[r]; sb += s0[r+1]; sc += s1[r]; sd += s1[r+1];
      }
      float rsum = (sa + sb) + (sc + sd);
      rsum += __shfl_xor(rsum, 32);
      l_run += rsum;

      // ---- P^T -> packed f16 pairs
      u32 pk[2][8];
#pragma unroll
      for (int p = 0; p < 8; ++p) {
        pk[0][p] = pkrtz_u(s0[2*p], s0[2*p+1]);
        pk[1][p] = pkrtz_u(s1[2*p], s1[2*p+1]);
      }

      // ---- out^T += Vt . P^T  (B-frags via permlane32_swap, distinct operands)
      __builtin_amdgcn_s_setprio(1);
#pragma unroll
      for (int ks = 0; ks < 4; ++ks) {
        const int c = ks >> 1, base = (ks & 1) * 4;
        auto r0 = __builtin_amdgcn_permlane32_swap((int)pk[c][base + 0], (int)pk[c][base + 2], false, false);
        auto r1 = __builtin_amdgcn_permlane32_swap((int)pk[c][base + 1], (int)pk[c][base + 3], false, false);
        u32x4 bw;
        bw[0] = (u32)r0[0];
        bw[1] = (u32)r1[0];
        bw[2] = (u32)r0[1];
        bw[3] = (u32)r1[1];
        const f16x8 pb = __builtin_bit_cast(f16x8, bw);
        const int cs = ((ks * 2 + (hi ? 1 : 0)) ^ sw) * 8;
        const f16x8 va0 = *(const f16x8*)&vb[l31 * 64 + cs];
        const f16x8 va1 = *(const f16x8*)&vb[(32 + l31) * 64 + cs];
        acc0 = __builtin_amdgcn_mfma_f32_32x32x16_f16(va0, pb, acc0, 0, 0, 0);
        acc1 = __builtin_amdgcn_mfma_f32_32x32x16_f16(va1, pb, acc1, 0, 0, 0);
      }
      __builtin_amdgcn_s_setprio(0);
    }

    __syncthreads();
    cur ^= 1;
  }

  // ---- epilogue: normalize, out^T -> LDS transpose (72-pitch) -> store
  _Float16* tr = &smem[0][0][0] + wid * 2304;     // 32 rows x 72 per wave
  const float invl = rcp(l_run);
#pragma unroll
  for (int r = 0; r < 16; ++r) {
    const int d = (r & 3) + 8 * (r >> 2) + (hi ? 4 : 0);
    tr[l31 * 72 + d]      = (_Float16)(acc0[r] * invl);
    tr[l31 * 72 + 32 + d] = (_Float16)(acc1[r] * invl);
  }
  __syncthreads();
  if (partial) {
    if (!hi) ps[u * 128 + wid * 32 + l31] = m_run + lg2(l_run);
    _Float16* dst = (u < 832) ? (pO0 + (size_t)u * 8192)
                              : (pO1 + (size_t)(u - 832) * 8192);
#pragma unroll
    for (int cc = 0; cc < 4; ++cc) {
      const int qq = cc * 8 + (lane >> 3), c8 = lane & 7;
      const f16x8 v = *(const f16x8*)&tr[qq * 72 + c8 * 8];
      *(f16x8*)&dst[(wid * 32 + qq) * 64 + c8 * 8] = v;
    }
  } else {
#pragma unroll
    for (int cc = 0; cc < 4; ++cc) {
      const int qq = cc * 8 + (lane >> 3), c8 = lane & 7;
      const f16x8 v = *(const f16x8*)&tr[qq * 72 + c8 * 8];
      *(f16x8*)&Om[(size_t)(q0w + qq) * DMODEL + h * HDIM + c8 * 8] = v;
    }
  }
}

// ---------------------------------------------------------------- combine partials (q >= 1024)
__global__ __launch_bounds__(256)
void combine_k(const _Float16* __restrict__ pO0,
               const _Float16* __restrict__ pO1,
               const float* __restrict__ ps,
               _Float16* __restrict__ Om)
{
  const int t  = blockIdx.x * 256 + threadIdx.x;   // 0..393215
  const int d8 = t & 7;
  const int hh = (t >> 3) & 15;
  const int q  = 1024 + (t >> 7);
  const int j  = q >> 7;                           // 8..31 (128-row blocks)
  const int qr = q & 127;
  const int parts = (j >= 24) ? 4 : (j >= 16) ? 3 : 2;
  const int off   = (j >= 24) ? 40 + (j - 24) * 4
                  : (j >= 16) ? 16 + (j - 16) * 3
                  :             (j - 8) * 2;
  const int u0 = hh * 72 + off;

  float sv[4];
#pragma unroll
  for (int p = 0; p < 4; ++p)
    sv[p] = (p < parts) ? ps[(u0 + p) * 128 + qr] : -1e30f;
  const float S = fmaxf(fmaxf(sv[0], sv[1]), fmaxf(sv[2], sv[3]));

  float o[8] = {0.f, 0.f, 0.f, 0.f, 0.f, 0.f, 0.f, 0.f};
  float tot = 0.f;
#pragma unroll
  for (int p = 0; p < 4; ++p) {
    if (p < parts) {
      const float w = ex2(sv[p] - S);
      tot += w;
      const int uu = u0 + p;
      const _Float16* pp = (uu < 832) ? (pO0 + (size_t)uu * 8192)
                                      : (pO1 + (size_t)(uu - 832) * 8192);
      const f16x8 v = *(const f16x8*)&pp[qr * 64 + d8 * 8];
#pragma unroll
      for (int e = 0; e < 8; ++e) o[e] += w * (float)v[e];
    }
  }
  const float inv = rcp(tot);
  f16x8 ov;
#pragma unroll
  for (int e = 0; e < 8; ++e) ov[e] = (_Float16)(o[e] * inv);
  *(f16x8*)&Om[(size_t)q * DMODEL + hh * 64 + d8 * 8] = ov;
}

// ---------------------------------------------------------------- launch
extern "C" void kernel_launch(void* const* d_in, const int* in_sizes, int n_in,
                              void* d_out, int out_size, void* d_ws, size_t ws_size,
                              hipStream_t stream)
{
  const float* hs = (const float*)d_in[0];
  const float* ts = (const float*)d_in[1];
  const float* Wq = (const float*)d_in[2];
  const float* bq = (const float*)d_in[3];
  const float* Wk = (const float*)d_in[4];
  const float* bk = (const float*)d_in[5];
  const float* Wv = (const float*)d_in[6];
  const float* bv = (const float*)d_in[7];
  const float* Wo = (const float*)d_in[8];
  float* out = (float*)d_out;

  char* ws = (char*)d_ws;
  const size_t MB = 1024 * 1024;
  _Float16* hsb  = (_Float16*)(ws + 0 * MB);    // [S][D] 8MB (dead after gemm_qkv)
  _Float16* wqb  = (_Float16*)(ws + 8 * MB);    // 2MB    (dead after gemm_qkv)
  _Float16* wkb  = (_Float16*)(ws + 10 * MB);
  _Float16* wvb  = (_Float16*)(ws + 12 * MB);
  _Float16* wob  = (_Float16*)(ws + 14 * MB);   // live until gemm_o
  _Float16* Qb   = (_Float16*)(ws + 16 * MB);
  _Float16* Kb   = (_Float16*)(ws + 24 * MB);
  _Float16* Vtb  = (_Float16*)(ws + 32 * MB);   // [D][S] transposed
  _Float16* attb = (_Float16*)(ws + 40 * MB);
  // attention partial scratch: units 0..831 in dead ws cast region,
  // units 832..1151 in d_out (dead until gemm_o overwrites it).
  _Float16* pO0  = (_Float16*)(ws + 0 * MB);            // 832 x 16KB = 13.0MB
  _Float16* pO1  = (_Float16*)d_out;                    // 320 x 16KB = 5.0MB (of 16MB)
  float*    ps   = (float*)   (ws + (size_t)13631488);  // 1152 x 512B = 590KB (< 14MB)

  cast_all_k<<<dim3(8192), dim3(256), 0, stream>>>(hs, Wq, Wk, Wv, Wo,
                                                   hsb, wqb, wkb, wvb, wob);

  gemm_qkv<<<dim3(768), dim3(256), 0, stream>>>(
      hsb, wqb, bq, bk, bv, ts, Qb, Kb, Vtb);

  attn_fwd<<<dim3(1280), dim3(256), 0, stream>>>(Qb, Kb, Vtb, attb, pO0, pO1, ps);
  combine_k<<<dim3(1536), dim3(256), 0, stream>>>(pO0, pO1, ps, attb);

  gemm_o<<<dim3(512), dim3(256), 0, stream>>>(attb, wob, out);
}

// Round 15
// 136.110 us; speedup vs baseline: 2.9900x; 1.0080x over previous
//
#include <hip/hip_runtime.h>

#define S_LEN  4096
#define DMODEL 1024
#define NHEAD  16
#define HDIM   64

typedef float    f32x4  __attribute__((ext_vector_type(4)));
typedef float    f32x16 __attribute__((ext_vector_type(16)));
typedef _Float16 f16x8  __attribute__((ext_vector_type(8)));
typedef _Float16 f16x4v __attribute__((ext_vector_type(4)));
typedef __fp16   fp16x2 __attribute__((ext_vector_type(2)));
typedef unsigned int u32;
typedef u32 u32x4 __attribute__((ext_vector_type(4)));

// ---------------------------------------------------------------- helpers
__device__ __forceinline__ void gl2lds16(const _Float16* g, _Float16* l) {
  __builtin_amdgcn_global_load_lds(
      (const __attribute__((address_space(1))) unsigned int*)g,
      (__attribute__((address_space(3))) unsigned int*)l, 16, 0, 0);
}

__device__ __forceinline__ u32 pkrtz_u(float a, float b) {
  fp16x2 h = __builtin_amdgcn_cvt_pkrtz(a, b);
  return __builtin_bit_cast(u32, h);
}

__device__ __forceinline__ float m3(float a, float b, float c) {
  return fmaxf(fmaxf(a, b), c);   // clang fuses to v_max3_f32
}

// native transcendentals (bare v_exp/v_log/v_rcp, no libm guard code)
__device__ __forceinline__ float ex2(float x) { return __builtin_amdgcn_exp2f(x); }
__device__ __forceinline__ float lg2(float x) { return __builtin_amdgcn_logf(x); }
__device__ __forceinline__ float rcp(float x) { return __builtin_amdgcn_rcpf(x); }

// ---------------------------------------------------------------- merged casts
__global__ void cast_all_k(const float* __restrict__ hs,
                           const float* __restrict__ a, const float* __restrict__ b,
                           const float* __restrict__ c, const float* __restrict__ d,
                           _Float16* __restrict__ ohs,
                           _Float16* __restrict__ oa, _Float16* __restrict__ ob,
                           _Float16* __restrict__ oc, _Float16* __restrict__ od) {
  const int bid = blockIdx.x;
  const float* in;
  _Float16* out;
  int local;
  if (bid < 4096) {
    in = hs; out = ohs; local = bid;
  } else {
    const int seg = (bid - 4096) >> 10;
    local = (bid - 4096) & 1023;
    in  = seg == 0 ? a  : seg == 1 ? b  : seg == 2 ? c  : d;
    out = seg == 0 ? oa : seg == 1 ? ob : seg == 2 ? oc : od;
  }
  const int i = (local * 256 + threadIdx.x) * 4;
  const float4 v = *(const float4*)(in + i);
  f16x4v o = { (_Float16)v.x, (_Float16)v.y, (_Float16)v.z, (_Float16)v.w };
  *(f16x4v*)(out + i) = o;
}

// ---------------------------------------------------------------- fused QKV GEMM
// 1D grid 768, XCD-chunked (xcd owns 3 n-tiles; B-panel L2-resident).
__global__ __launch_bounds__(256)
void gemm_qkv(const _Float16* __restrict__ A,
              const _Float16* __restrict__ Bw,
              const float* __restrict__ bq,
              const float* __restrict__ bk,
              const float* __restrict__ bv,
              const float* __restrict__ ts,
              _Float16* __restrict__ Qb,
              _Float16* __restrict__ Kb,
              _Float16* __restrict__ Vtb)
{
  __shared__ _Float16 lA[128 * 64];
  __shared__ _Float16 lB[128 * 64];

  const int tid  = threadIdx.x;
  const int wid  = tid >> 6;
  const int lane = tid & 63;
  const int l16  = lane & 15;
  const int lg   = lane >> 4;
  const int wr = wid >> 1, wc = wid & 1;
  const int bid = blockIdx.x, xcd = bid & 7, ci = bid >> 3;   // ci 0..95
  const int n0 = (xcd * 3 + ci / 32) * 128;
  const int m0 = (ci & 31) * 128;
  const int K = DMODEL, M = S_LEN;

  const int lrow   = lane >> 3;
  const int gchunk = (lane & 7) ^ lrow;

  f32x4 acc[4][4] = {};

  for (int k0 = 0; k0 < K; k0 += 64) {
#pragma unroll
    for (int it = 0; it < 4; ++it) {
      const int rbase = (it * 4 + wid) * 8;
      gl2lds16(A  + (size_t)(m0 + rbase + lrow) * K + k0 + gchunk * 8, &lA[rbase * 64]);
      gl2lds16(Bw + (size_t)(n0 + rbase + lrow) * K + k0 + gchunk * 8, &lB[rbase * 64]);
    }
    __syncthreads();
#pragma unroll
    for (int kk = 0; kk < 2; ++kk) {
      f16x8 af[4], bfr[4];
#pragma unroll
      for (int mr = 0; mr < 4; ++mr) {
        const int row = wr * 64 + mr * 16 + l16;
        const int ch  = (kk * 4 + lg) ^ (l16 & 7);
        af[mr] = *(const f16x8*)&lA[row * 64 + ch * 8];
      }
#pragma unroll
      for (int nr = 0; nr < 4; ++nr) {
        const int row = wc * 64 + nr * 16 + l16;
        const int ch  = (kk * 4 + lg) ^ (l16 & 7);
        bfr[nr] = *(const f16x8*)&lB[row * 64 + ch * 8];
      }
#pragma unroll
      for (int mr = 0; mr < 4; ++mr)
#pragma unroll
        for (int nr = 0; nr < 4; ++nr)
          acc[mr][nr] = __builtin_amdgcn_mfma_f32_16x16x32_f16(af[mr], bfr[nr], acc[mr][nr], 0, 0, 0);
    }
    __syncthreads();
  }

  if (n0 >= 2048) {           // ---- V: bias + transposed store
    const int dbase = n0 - 2048;
    float bvv[4];
#pragma unroll
    for (int nr = 0; nr < 4; ++nr) bvv[nr] = bv[dbase + wc * 64 + nr * 16 + l16];
#pragma unroll
    for (int mr = 0; mr < 4; ++mr) {
      const int mbase = m0 + wr * 64 + mr * 16 + lg * 4;
#pragma unroll
      for (int nr = 0; nr < 4; ++nr) {
        const int d = dbase + wc * 64 + nr * 16 + l16;
        f16x4v o = { (_Float16)(acc[mr][nr][0] + bvv[nr]),
                     (_Float16)(acc[mr][nr][1] + bvv[nr]),
                     (_Float16)(acc[mr][nr][2] + bvv[nr]),
                     (_Float16)(acc[mr][nr][3] + bvv[nr]) };
        *(f16x4v*)&Vtb[(size_t)d * M + mbase] = o;
      }
    }
  } else {                    // ---- Q or K: bias + CT-RoPE (native sin/cos, revolutions)
    _Float16* O = (n0 < 1024) ? Qb : Kb;
    const float* bias = (n0 < 1024) ? bq : bk;
    const int nloc = n0 & 1023;
    float bvv[4];
#pragma unroll
    for (int nr = 0; nr < 4; ++nr) bvv[nr] = bias[nloc + wc * 64 + nr * 16 + l16];
    const float L2T  = 13.287712379549449f / 32.0f;   // log2(10000)/32
    const float R2PI = 0.15915494309189535f;          // 1/(2*pi)
    const float inv0 = ex2(-(float)l16 * L2T) * R2PI;         // rev per unit t
    const float inv1 = ex2(-(float)(l16 + 16) * L2T) * R2PI;
#pragma unroll
    for (int mr = 0; mr < 4; ++mr)
#pragma unroll
      for (int r = 0; r < 4; ++r) {
        const int m = m0 + wr * 64 + mr * 16 + lg * 4 + r;
        const float t = ts[m];
        const float a0 = __builtin_amdgcn_fractf(t * inv0);
        const float a1 = __builtin_amdgcn_fractf(t * inv1);
        const float s0 = __builtin_amdgcn_sinf(a0), c0 = __builtin_amdgcn_cosf(a0);
        const float s1 = __builtin_amdgcn_sinf(a1), c1 = __builtin_amdgcn_cosf(a1);
        const float p0 = acc[mr][0][r] + bvv[0];
        const float p1 = acc[mr][1][r] + bvv[1];
        const float p2 = acc[mr][2][r] + bvv[2];
        const float p3 = acc[mr][3][r] + bvv[3];
        const size_t base = (size_t)m * DMODEL + nloc + wc * 64 + l16;
        O[base + 0 ] = (_Float16)(p0 * c0 - p2 * s0);
        O[base + 16] = (_Float16)(p1 * c1 - p3 * s1);
        O[base + 32] = (_Float16)(p2 * c0 + p0 * s0);
        O[base + 48] = (_Float16)(p3 * c1 + p1 * s1);
      }
  }
}

// ---------------------------------------------------------------- O-proj GEMM (f32 out)
// 1D grid 512, 64x128 tile, XCD-chunked.
__global__ __launch_bounds__(256)
void gemm_o(const _Float16* __restrict__ A,
            const _Float16* __restrict__ Bw,
            float* __restrict__ O)
{
  __shared__ _Float16 lA[64 * 64];
  __shared__ _Float16 lB[128 * 64];

  const int tid  = threadIdx.x;
  const int wid  = tid >> 6;
  const int lane = tid & 63;
  const int l16  = lane & 15;
  const int lg   = lane >> 4;
  const int wr = wid >> 1, wc = wid & 1;
  const int bid = blockIdx.x, xcd = bid & 7, ci = bid >> 3;   // ci 0..63
  const int n0 = xcd * 128;
  const int m0 = ci * 64;
  const int K = DMODEL, N = DMODEL;

  const int lrow   = lane >> 3;
  const int gchunk = (lane & 7) ^ lrow;

  f32x4 acc[2][4] = {};

  for (int k0 = 0; k0 < K; k0 += 64) {
#pragma unroll
    for (int it = 0; it < 2; ++it) {
      const int rbase = (it * 4 + wid) * 8;
      gl2lds16(A + (size_t)(m0 + rbase + lrow) * K + k0 + gchunk * 8, &lA[rbase * 64]);
    }
#pragma unroll
    for (int it = 0; it < 4; ++it) {
      const int rbase = (it * 4 + wid) * 8;
      gl2lds16(Bw + (size_t)(n0 + rbase + lrow) * K + k0 + gchunk * 8, &lB[rbase * 64]);
    }
    __syncthreads();
#pragma unroll
    for (int kk = 0; kk < 2; ++kk) {
      f16x8 af[2], bfr[4];
#pragma unroll
      for (int mr = 0; mr < 2; ++mr) {
        const int row = wr * 32 + mr * 16 + l16;
        const int ch  = (kk * 4 + lg) ^ (l16 & 7);
        af[mr] = *(const f16x8*)&lA[row * 64 + ch * 8];
      }
#pragma unroll
      for (int nr = 0; nr < 4; ++nr) {
        const int row = wc * 64 + nr * 16 + l16;
        const int ch  = (kk * 4 + lg) ^ (l16 & 7);
        bfr[nr] = *(const f16x8*)&lB[row * 64 + ch * 8];
      }
#pragma unroll
      for (int mr = 0; mr < 2; ++mr)
#pragma unroll
        for (int nr = 0; nr < 4; ++nr)
          acc[mr][nr] = __builtin_amdgcn_mfma_f32_16x16x32_f16(af[mr], bfr[nr], acc[mr][nr], 0, 0, 0);
    }
    __syncthreads();
  }

#pragma unroll
  for (int mr = 0; mr < 2; ++mr)
#pragma unroll
    for (int r = 0; r < 4; ++r) {
      const int m = m0 + wr * 32 + mr * 16 + lg * 4 + r;
#pragma unroll
      for (int nr = 0; nr < 4; ++nr) {
        const int n = n0 + wc * 64 + nr * 16 + l16;
        O[(size_t)m * N + n] = acc[mr][nr][r];
      }
    }
}

// ---------------------------------------------------------------- flash attention v11
// v9 structure + native exp2 + POINTER-INCREMENT STAGING: the four
// global source pointers advance by constant strides per kv-tile
// (K: +64 rows, Vt: +64 cols) instead of full 64-bit recompute.
__device__ __forceinline__ int part_off(int jb) {
  if (jb >= 24) return 40 + (jb - 24) * 4;
  if (jb >= 16) return 16 + (jb - 16) * 3;
  return (jb - 8) * 2;
}

__global__ __launch_bounds__(256, 4)
void attn_fwd(const _Float16* __restrict__ Q,
              const _Float16* __restrict__ Km,
              const _Float16* __restrict__ Vt,
              _Float16* __restrict__ Om,
              _Float16* __restrict__ pO0,
              _Float16* __restrict__ pO1,
              float* __restrict__ ps)
{
  __shared__ __align__(16) _Float16 smem[2 * 2 * 64 * 64];   // 32KB: buf*8192 + (K:0|V:4096)

  const int tid  = threadIdx.x;
  const int wid  = tid >> 6, lane = tid & 63;
  const int l31  = lane & 31;
  const bool hi  = (lane & 32) != 0;
  const int flat = blockIdx.x, xcd = flat & 7, idx = flat >> 3;  // idx 0..159
  const int h    = xcd * 2 + (idx & 1);
  const int slot = idx >> 1;                  // 0..79, ascending = heaviest first
  int jb, part, parts;
  if (slot < 32)      { jb = 31 - (slot >> 2);              part = slot & 3;  parts = 4; }
  else if (slot < 56) { const int t = slot - 32; jb = 23 - t / 3; part = t % 3; parts = 3; }
  else if (slot < 72) { const int t = slot - 56; jb = 15 - (t >> 1); part = t & 1; parts = 2; }
  else                { jb = 79 - slot;                     part = 0;        parts = 1; }
  const int nt  = 2 * jb + 2;
  const int kt0 = (nt * part) / parts, kt1 = (nt * (part + 1)) / parts;
  const bool partial = parts > 1;
  const int u = partial ? (h * 72 + part_off(jb) + part) : 0;
  const int q0w = jb * 128 + wid * 32;
  const int sw  = l31 & 7;                    // LDS read swizzle

  // ---- staging geometry (per-thread constants) + pointer accumulators
  const int rb0  = wid * 16;                  // wave-uniform LDS row bases
  const int rb1  = wid * 16 + 8;
  const int row0 = rb0 + (lane >> 3);         // per-lane source rows
  const int row1 = rb1 + (lane >> 3);
  const int g0   = (lane & 7) ^ (row0 & 7);   // pre-swizzled source chunks
  const int g1   = (lane & 7) ^ (row1 & 7);
  const _Float16* kp0 = Km + (size_t)(kt0 * 64 + row0) * DMODEL + h * HDIM + g0 * 8;
  const _Float16* kp1 = Km + (size_t)(kt0 * 64 + row1) * DMODEL + h * HDIM + g1 * 8;
  const _Float16* vp0 = Vt + (size_t)(h * HDIM + row0) * S_LEN + kt0 * 64 + g0 * 8;
  const _Float16* vp1 = Vt + (size_t)(h * HDIM + row1) * S_LEN + kt0 * 64 + g1 * 8;
  const int KSTRIDE = 64 * DMODEL;            // f16 elems per kv-tile (K rows)
  const int VSTRIDE = 64;                     // f16 elems per kv-tile (Vt cols)

  // Q B-fragments, pre-scaled by (1/sqrt(64))*log2(e)
  f16x8 qf[4];
  {
    const float qs = 0.18033688f;
    const size_t qbase = (size_t)(q0w + l31) * DMODEL + h * HDIM + (hi ? 8 : 0);
#pragma unroll
    for (int ks = 0; ks < 4; ++ks) {
      f16x8 t = *(const f16x8*)&Q[qbase + ks * 16];
#pragma unroll
      for (int e = 0; e < 8; ++e) qf[ks][e] = (_Float16)((float)t[e] * qs);
    }
  }

  f32x16 acc0, acc1;
#pragma unroll
  for (int r = 0; r < 16; ++r) { acc0[r] = 0.f; acc1[r] = 0.f; }
  float m_run = 0.f, l_run = 0.f;   // scores tracked as S - m_run; m starts 0

  // initial stage into buffer 0
  gl2lds16(kp0, &smem[rb0 * 64]);
  gl2lds16(kp1, &smem[rb1 * 64]);
  gl2lds16(vp0, &smem[4096 + rb0 * 64]);
  gl2lds16(vp1, &smem[4096 + rb1 * 64]);
  __syncthreads();
  int cur = 0;

  for (int kt = kt0; kt < kt1; ++kt) {
    if (kt + 1 < kt1) {
      kp0 += KSTRIDE; kp1 += KSTRIDE; vp0 += VSTRIDE; vp1 += VSTRIDE;
      const int nb = (cur ^ 1) * 8192;
      gl2lds16(kp0, &smem[nb + rb0 * 64]);
      gl2lds16(kp1, &smem[nb + rb1 * 64]);
      gl2lds16(vp0, &smem[nb + 4096 + rb0 * 64]);
      gl2lds16(vp1, &smem[nb + 4096 + rb1 * 64]);
    }

    const int kv0 = kt * 64;
    if (kv0 <= q0w + 31) {           // wave has at least one unmasked column
      const _Float16* kb = &smem[cur * 8192];
      const _Float16* vb = &smem[cur * 8192 + 4096];

      // ---- S^T - m_run = K . Q^T + (-m_run)  (rows = kv, cols = q)
      f32x16 s0, s1;
#pragma unroll
      for (int r = 0; r < 16; ++r) { s0[r] = -m_run; s1[r] = -m_run; }
      __builtin_amdgcn_s_setprio(1);
#pragma unroll
      for (int ks = 0; ks < 4; ++ks) {
        const int cs = ((ks * 2 + (hi ? 1 : 0)) ^ sw) * 8;
        const f16x8 ka0 = *(const f16x8*)&kb[l31 * 64 + cs];
        const f16x8 ka1 = *(const f16x8*)&kb[(32 + l31) * 64 + cs];
        s0 = __builtin_amdgcn_mfma_f32_32x32x16_f16(ka0, qf[ks], s0, 0, 0, 0);
        s1 = __builtin_amdgcn_mfma_f32_32x32x16_f16(ka1, qf[ks], s1, 0, 0, 0);
      }
      __builtin_amdgcn_s_setprio(0);

      if (kv0 + 63 > q0w) {          // diagonal tile: causal mask
        const int q = q0w + l31;
#pragma unroll
        for (int r = 0; r < 16; ++r) {
          const int kvr = kv0 + (r & 3) + 8 * (r >> 2) + (hi ? 4 : 0);
          if (kvr > q)      s0[r] = -1e30f;
          if (kvr + 32 > q) s1[r] = -1e30f;
        }
      }

      // ---- online softmax (exp2 domain), lane-local rows, defer-max
      float t10[10];
#pragma unroll
      for (int p = 0; p < 5; ++p) {
        t10[p]     = m3(s0[3*p], s0[3*p+1], s0[3*p+2]);
        t10[5 + p] = m3(s1[3*p], s1[3*p+1], s1[3*p+2]);
      }
      float u0 = m3(t10[0], t10[1], t10[2]);
      float u1 = m3(t10[3], t10[4], s0[15]);
      float u2 = m3(t10[5], t10[6], t10[7]);
      float u3 = m3(t10[8], t10[9], s1[15]);
      float pm = fmaxf(m3(u0, u1, u2), u3);
      pm = fmaxf(pm, __shfl_xor(pm, 32));

      if (!__all(pm <= 10.f)) {      // rescale (rare after first tile)
        m_run += pm;
        const float scl = ex2(-pm);
        l_run *= scl;
#pragma unroll
        for (int r = 0; r < 16; ++r) { acc0[r] *= scl; acc1[r] *= scl; }
#pragma unroll
        for (int r = 0; r < 16; ++r) { s0[r] -= pm; s1[r] -= pm; }
      }

      float sa = 0.f, sb = 0.f, sc = 0.f, sd = 0.f;
#pragma unroll
      for (int r = 0; r < 16; r += 2) {
        s0[r]   = ex2(s0[r]);
        s0[r+1] = ex2(s0[r+1]);
        s1[r]   = ex2(s1[r]);
        s1[r+1] = ex2(s1[r+1]);
        sa += s0[r]; sb += s0[r+1]; sc += s1[r]; sd += s1[r+1];
      }
      float rsum = (sa + sb) + (sc + sd);
      rsum += __shfl_xor(rsum, 32);
      l_run += rsum;

      // ---- P^T -> packed f16 pairs
      u32 pk[2][8];
#pragma unroll
      for (int p = 0; p < 8; ++p) {
        pk[0][p] = pkrtz_u(s0[2*p], s0[2*p+1]);
        pk[1][p] = pkrtz_u(s1[2*p], s1[2*p+1]);
      }

      // ---- out^T += Vt . P^T  (B-frags via permlane32_swap, distinct operands)
      __builtin_amdgcn_s_setprio(1);
#pragma unroll
      for (int ks = 0; ks < 4; ++ks) {
        const int c = ks >> 1, base = (ks & 1) * 4;
        auto r0 = __builtin_amdgcn_permlane32_swap((int)pk[c][base + 0], (int)pk[c][base + 2], false, false);
        auto r1 = __builtin_amdgcn_permlane32_swap((int)pk[c][base + 1], (int)pk[c][base + 3], false, false);
        u32x4 bw;
        bw[0] = (u32)r0[0];
        bw[1] = (u32)r1[0];
        bw[2] = (u32)r0[1];
        bw[3] = (u32)r1[1];
        const f16x8 pb = __builtin_bit_cast(f16x8, bw);
        const int cs = ((ks * 2 + (hi ? 1 : 0)) ^ sw) * 8;
        const f16x8 va0 = *(const f16x8*)&vb[l31 * 64 + cs];
        const f16x8 va1 = *(const f16x8*)&vb[(32 + l31) * 64 + cs];
        acc0 = __builtin_amdgcn_mfma_f32_32x32x16_f16(va0, pb, acc0, 0, 0, 0);
        acc1 = __builtin_amdgcn_mfma_f32_32x32x16_f16(va1, pb, acc1, 0, 0, 0);
      }
      __builtin_amdgcn_s_setprio(0);
    }

    __syncthreads();
    cur ^= 1;
  }

  // ---- epilogue: normalize, out^T -> LDS transpose (72-pitch) -> store
  _Float16* tr = &smem[0] + wid * 2304;     // 32 rows x 72 per wave
  const float invl = rcp(l_run);
#pragma unroll
  for (int r = 0; r < 16; ++r) {
    const int d = (r & 3) + 8 * (r >> 2) + (hi ? 4 : 0);
    tr[l31 * 72 + d]      = (_Float16)(acc0[r] * invl);
    tr[l31 * 72 + 32 + d] = (_Float16)(acc1[r] * invl);
  }
  __syncthreads();
  if (partial) {
    if (!hi) ps[u * 128 + wid * 32 + l31] = m_run + lg2(l_run);
    _Float16* dst = (u < 832) ? (pO0 + (size_t)u * 8192)
                              : (pO1 + (size_t)(u - 832) * 8192);
#pragma unroll
    for (int cc = 0; cc < 4; ++cc) {
      const int qq = cc * 8 + (lane >> 3), c8 = lane & 7;
      const f16x8 v = *(const f16x8*)&tr[qq * 72 + c8 * 8];
      *(f16x8*)&dst[(wid * 32 + qq) * 64 + c8 * 8] = v;
    }
  } else {
#pragma unroll
    for (int cc = 0; cc < 4; ++cc) {
      const int qq = cc * 8 + (lane >> 3), c8 = lane & 7;
      const f16x8 v = *(const f16x8*)&tr[qq * 72 + c8 * 8];
      *(f16x8*)&Om[(size_t)(q0w + qq) * DMODEL + h * HDIM + c8 * 8] = v;
    }
  }
}

// ---------------------------------------------------------------- combine partials (q >= 1024)
__global__ __launch_bounds__(256)
void combine_k(const _Float16* __restrict__ pO0,
               const _Float16* __restrict__ pO1,
               const float* __restrict__ ps,
               _Float16* __restrict__ Om)
{
  const int t  = blockIdx.x * 256 + threadIdx.x;   // 0..393215
  const int d8 = t & 7;
  const int hh = (t >> 3) & 15;
  const int q  = 1024 + (t >> 7);
  const int j  = q >> 7;                           // 8..31 (128-row blocks)
  const int qr = q & 127;
  const int parts = (j >= 24) ? 4 : (j >= 16) ? 3 : 2;
  const int off   = (j >= 24) ? 40 + (j - 24) * 4
                  : (j >= 16) ? 16 + (j - 16) * 3
                  :             (j - 8) * 2;
  const int u0 = hh * 72 + off;

  float sv[4];
#pragma unroll
  for (int p = 0; p < 4; ++p)
    sv[p] = (p < parts) ? ps[(u0 + p) * 128 + qr] : -1e30f;
  const float S = fmaxf(fmaxf(sv[0], sv[1]), fmaxf(sv[2], sv[3]));

  float o[8] = {0.f, 0.f, 0.f, 0.f, 0.f, 0.f, 0.f, 0.f};
  float tot = 0.f;
#pragma unroll
  for (int p = 0; p < 4; ++p) {
    if (p < parts) {
      const float w = ex2(sv[p] - S);
      tot += w;
      const int uu = u0 + p;
      const _Float16* pp = (uu < 832) ? (pO0 + (size_t)uu * 8192)
                                      : (pO1 + (size_t)(uu - 832) * 8192);
      const f16x8 v = *(const f16x8*)&pp[qr * 64 + d8 * 8];
#pragma unroll
      for (int e = 0; e < 8; ++e) o[e] += w * (float)v[e];
    }
  }
  const float inv = rcp(tot);
  f16x8 ov;
#pragma unroll
  for (int e = 0; e < 8; ++e) ov[e] = (_Float16)(o[e] * inv);
  *(f16x8*)&Om[(size_t)q * DMODEL + hh * 64 + d8 * 8] = ov;
}

// ---------------------------------------------------------------- launch
extern "C" void kernel_launch(void* const* d_in, const int* in_sizes, int n_in,
                              void* d_out, int out_size, void* d_ws, size_t ws_size,
                              hipStream_t stream)
{
  const float* hs = (const float*)d_in[0];
  const float* ts = (const float*)d_in[1];
  const float* Wq = (const float*)d_in[2];
  const float* bq = (const float*)d_in[3];
  const float* Wk = (const float*)d_in[4];
  const float* bk = (const float*)d_in[5];
  const float* Wv = (const float*)d_in[6];
  const float* bv = (const float*)d_in[7];
  const float* Wo = (const float*)d_in[8];
  float* out = (float*)d_out;

  char* ws = (char*)d_ws;
  const size_t MB = 1024 * 1024;
  _Float16* hsb  = (_Float16*)(ws + 0 * MB);    // [S][D] 8MB (dead after gemm_qkv)
  _Float16* wqb  = (_Float16*)(ws + 8 * MB);    // 2MB    (dead after gemm_qkv)
  _Float16* wkb  = (_Float16*)(ws + 10 * MB);
  _Float16* wvb  = (_Float16*)(ws + 12 * MB);
  _Float16* wob  = (_Float16*)(ws + 14 * MB);   // live until gemm_o
  _Float16* Qb   = (_Float16*)(ws + 16 * MB);
  _Float16* Kb   = (_Float16*)(ws + 24 * MB);
  _Float16* Vtb  = (_Float16*)(ws + 32 * MB);   // [D][S] transposed
  _Float16* attb = (_Float16*)(ws + 40 * MB);
  // attention partial scratch: units 0..831 in dead ws cast region,
  // units 832..1151 in d_out (dead until gemm_o overwrites it).
  _Float16* pO0  = (_Float16*)(ws + 0 * MB);            // 832 x 16KB = 13.0MB
  _Float16* pO1  = (_Float16*)d_out;                    // 320 x 16KB = 5.0MB (of 16MB)
  float*    ps   = (float*)   (ws + (size_t)13631488);  // 1152 x 512B = 590KB (< 14MB)

  cast_all_k<<<dim3(8192), dim3(256), 0, stream>>>(hs, Wq, Wk, Wv, Wo,
                                                   hsb, wqb, wkb, wvb, wob);

  gemm_qkv<<<dim3(768), dim3(256), 0, stream>>>(
      hsb, wqb, bq, bk, bv, ts, Qb, Kb, Vtb);

  attn_fwd<<<dim3(1280), dim3(256), 0, stream>>>(Qb, Kb, Vtb, attb, pO0, pO1, ps);
  combine_k<<<dim3(1536), dim3(256), 0, stream>>>(pO0, pO1, ps, attb);

  gemm_o<<<dim3(512), dim3(256), 0, stream>>>(attb, wob, out);
}